// Round 18
// baseline (387.392 us; speedup 1.0000x reference)
//
#include <hip/hip_runtime.h>
#include <hip/hip_bf16.h>
#include <cmath>

typedef unsigned short u16;
typedef __bf16 bf16x8 __attribute__((ext_vector_type(8)));
typedef float floatx4 __attribute__((ext_vector_type(4)));

#define SQ 1029
#define DM 768
#define NH 12
#define SQP 1088   // 17*64 tile coverage for attention
#define SSC 0.18033688011112042f   // 0.125 * log2(e), folded into q

// async global->LDS, 16B per lane; LDS dest = wave-uniform base + lane*16
#define GLD16(gp, lp) __builtin_amdgcn_global_load_lds( \
    (const __attribute__((address_space(1))) unsigned int*)(gp), \
    (__attribute__((address_space(3))) unsigned int*)(lp), 16, 0, 0)

// ---- workspace layout (bytes) ----
#define OFF_WQKV ((size_t)0)
#define OFF_WOUT ((size_t)3538944)
#define OFF_W1   ((size_t)4718592)
#define OFF_W2   ((size_t)9437184)
#define OFF_XF   ((size_t)14155776)
#define OFF_XWT  ((size_t)26800128)
#define OFF_QKV  ((size_t)39444480)
#define OFF_VT   ((size_t)77783040)
#define OFF_Y    ((size_t)91152384)
#define OFF_BQ   ((size_t)103796736)   // 2304 fp32 scaled qkv bias

__device__ __forceinline__ float bf2f(u16 u) {
  unsigned int x = ((unsigned int)u) << 16;
  float f; __builtin_memcpy(&f, &x, 4); return f;
}
__device__ __forceinline__ u16 f2bf(float f) {
  unsigned int x; __builtin_memcpy(&x, &f, 4);
  x = (x + 0x7fffu + ((x >> 16) & 1u)) >> 16;   // RNE
  return (u16)x;
}
__device__ __forceinline__ unsigned int pk_bf16(float a, float b) {
  __hip_bfloat162 h = __float22bfloat162_rn(make_float2(a, b));
  unsigned int u; __builtin_memcpy(&u, &h, 4); return u;
}

__device__ __forceinline__ void blockReduce2(float& s1, float& s2) {
  #pragma unroll
  for (int o = 32; o > 0; o >>= 1) { s1 += __shfl_xor(s1, o); s2 += __shfl_xor(s2, o); }
  __shared__ float t1[4], t2[4];
  const int w = threadIdx.x >> 6;
  if ((threadIdx.x & 63) == 0) { t1[w] = s1; t2[w] = s2; }
  __syncthreads();
  s1 = t1[0] + t1[1] + t1[2] + t1[3];
  s2 = t2[0] + t2[1] + t2[2] + t2[3];
}

// ---- all fp32 weights -> bf16 (q rows pre-scaled) + scaled qkv bias, one launch ----
__global__ __launch_bounds__(256) void convw_all(
    const float* __restrict__ a, const float* __restrict__ b,
    const float* __restrict__ c, const float* __restrict__ d,
    const float* __restrict__ bq, u16* __restrict__ dst, float* __restrict__ bqs) {
  int i = blockIdx.x * 256 + threadIdx.x;
  if (i >= 1770048) return;
  if (i >= 1769472) {                      // qkv bias tail: 576 float4 = 2304 fp32
    const int off = i - 1769472;
    float4 v = ((const float4*)bq)[off];
    if (off < 192) { v.x *= SSC; v.y *= SSC; v.z *= SSC; v.w *= SSC; }  // q entries
    ((float4*)bqs)[off] = v;
    return;
  }
  const float* src; int off;
  if (i < 442368)       { src = a; off = i; }
  else if (i < 589824)  { src = b; off = i - 442368; }
  else if (i < 1179648) { src = c; off = i - 589824; }
  else                  { src = d; off = i - 1179648; }
  float4 v = ((const float4*)src)[off];
  if (i < 147456) { v.x *= SSC; v.y *= SSC; v.z *= SSC; v.w *= SSC; }  // q rows of wqkv
  ushort4 o; o.x = f2bf(v.x); o.y = f2bf(v.y); o.z = f2bf(v.z); o.w = f2bf(v.w);
  ((ushort4*)dst)[i] = o;
}

// ---- LN1: feature rows (fused transpose, blocks 0..255) + token rows (blocks 256..295) ----
__global__ __launch_bounds__(256) void ln1_fused(
    const float* __restrict__ x, const float* __restrict__ ctx, const float* __restrict__ regt,
    const float* __restrict__ g, const float* __restrict__ be, u16* __restrict__ xwt) {
  const int bx = blockIdx.x;
  const int tid = threadIdx.x;
  if (bx >= 256) {                     // token rows: tokens+PE, LN1
    const int row = bx - 256;          // 0..39
    const int b = row / 5, s = row % 5;
    float v[3];
    #pragma unroll
    for (int i = 0; i < 3; ++i) {
      const int c = tid + i * 256;
      float tok = (s == 0) ? ctx[c] : regt[(s - 1) * DM + c];
      float e = (float)(2 * (c / 2)) * (1.0f / 768.0f);
      float ang = (float)s / powf(10000.0f, e);
      v[i] = tok + ((c & 1) ? cosf(ang) : sinf(ang));
    }
    float s1 = v[0] + v[1] + v[2];
    float s2 = v[0] * v[0] + v[1] * v[1] + v[2] * v[2];
    blockReduce2(s1, s2);
    const float mean = s1 * (1.0f / 768.0f);
    const float var = s2 * (1.0f / 768.0f) - mean * mean;
    const float rs = rsqrtf(fmaxf(var, 0.0f) + 1e-5f);
    #pragma unroll
    for (int i = 0; i < 3; ++i) {
      const int c = tid + i * 256;
      xwt[((size_t)b * SQ + s) * DM + c] = f2bf((v[i] - mean) * rs * g[c] + be[c]);
    }
    return;
  }
  // feature rows: x fp32 (8,768,1024) -> xwt rows 5.. ; 4 waves x 8 rows
  __shared__ u16 XT[32][772];
  const int b = bx >> 5, st = bx & 31;
  const int i2 = tid & 15, cj = tid >> 4;
  const int n0 = st * 32;
  #pragma unroll 4
  for (int ct = 0; ct < 48; ++ct) {
    const int c = ct * 16 + cj;
    const float2 v = *(const float2*)&x[((size_t)b * 768 + c) * 1024 + n0 + i2 * 2];
    XT[i2 * 2][c]     = f2bf(v.x);
    XT[i2 * 2 + 1][c] = f2bf(v.y);
  }
  __syncthreads();
  const int wave = tid >> 6, lane = tid & 63;
  float gr[12], br[12];
  #pragma unroll
  for (int k = 0; k < 12; ++k) { gr[k] = g[lane + k * 64]; br[k] = be[lane + k * 64]; }
  #pragma unroll
  for (int rr = 0; rr < 8; ++rr) {
    const int row = wave * 8 + rr;
    float v[12];
    float s1 = 0.f, s2 = 0.f;
    #pragma unroll
    for (int k = 0; k < 12; ++k) {
      v[k] = bf2f(XT[row][lane + k * 64]);
      s1 += v[k]; s2 += v[k] * v[k];
    }
    #pragma unroll
    for (int o = 32; o > 0; o >>= 1) { s1 += __shfl_xor(s1, o); s2 += __shfl_xor(s2, o); }
    const float mean = s1 * (1.0f / 768.0f);
    const float var = s2 * (1.0f / 768.0f) - mean * mean;
    const float rs = rsqrtf(fmaxf(var, 0.0f) + 1e-5f);
    u16* dst = xwt + ((size_t)b * SQ + 5 + n0 + row) * DM;
    #pragma unroll
    for (int k = 0; k < 12; ++k)
      dst[lane + k * 64] = f2bf((v[k] - mean) * rs * gr[k] + br[k]);
  }
}

// ---- LN2 vectorized: wave-per-row, ushort4 loads (8B/lane), uint2 stores ----
__global__ __launch_bounds__(256) void ln2k(
    const u16* __restrict__ y, const float* __restrict__ g, const float* __restrict__ be,
    u16* __restrict__ out) {
  const int row = blockIdx.x * 4 + (threadIdx.x >> 6);
  const int lane = threadIdx.x & 63;
  const u16* src = y + (size_t)row * DM;
  float v[12];
  float s1 = 0.f, s2 = 0.f;
  #pragma unroll
  for (int k = 0; k < 3; ++k) {
    const ushort4 u = *(const ushort4*)&src[k * 256 + lane * 4];
    const float a0 = bf2f(u.x), a1 = bf2f(u.y), a2 = bf2f(u.z), a3 = bf2f(u.w);
    v[k * 4 + 0] = a0; v[k * 4 + 1] = a1; v[k * 4 + 2] = a2; v[k * 4 + 3] = a3;
    s1 += (a0 + a1) + (a2 + a3);
    s2 += (a0 * a0 + a1 * a1) + (a2 * a2 + a3 * a3);
  }
  #pragma unroll
  for (int o = 32; o > 0; o >>= 1) { s1 += __shfl_xor(s1, o); s2 += __shfl_xor(s2, o); }
  const float mean = s1 * (1.0f / 768.0f);
  const float var = s2 * (1.0f / 768.0f) - mean * mean;
  const float rs = rsqrtf(fmaxf(var, 0.0f) + 1e-5f);
  u16* dst = out + (size_t)row * DM;
  #pragma unroll
  for (int k = 0; k < 3; ++k) {
    const float4 g4 = *(const float4*)&g[k * 256 + lane * 4];
    const float4 b4 = *(const float4*)&be[k * 256 + lane * 4];
    uint2 w;
    w.x = pk_bf16((v[k * 4 + 0] - mean) * rs * g4.x + b4.x,
                  (v[k * 4 + 1] - mean) * rs * g4.y + b4.y);
    w.y = pk_bf16((v[k * 4 + 2] - mean) * rs * g4.z + b4.z,
                  (v[k * 4 + 3] - mean) * rs * g4.w + b4.w);
    *(uint2*)&dst[k * 256 + lane * 4] = w;
  }
}

// ---- 128x128 GEMM, 4 waves (64x64/wave), BK=64 — proven baseline (out_proj, ffn1, ffn2) ----
template<int EPI, int K, int NB>
__global__ __launch_bounds__(256) void gemmk(
    const u16* __restrict__ A, const u16* __restrict__ W, const float* __restrict__ bias,
    const u16* __restrict__ res, u16* __restrict__ out, int M) {
  constexpr int N = NB * 128;
  __shared__ u16 SM[16384];
  u16* Asm = SM;
  u16* Bsm = SM + 8192;
  const int tid = threadIdx.x, wave = tid >> 6, lane = tid & 63, quad = lane >> 4, l16 = lane & 15;
  const int lin = blockIdx.x;
  constexpr int FULL = 64 * NB;
  int mb, nb;
  if (lin < FULL) { const int g = lin / (8 * NB); const int r = lin - g * 8 * NB; mb = g * 8 + (r & 7); nb = r >> 3; }
  else { mb = 64; nb = lin - FULL; }
  const int m0 = mb * 128, n0 = nb * 128;
  const int wm = wave & 1, wn = wave >> 1;

  const u16* Ap[4]; const u16* Wp[4]; u16* la[4]; u16* lb[4];
  #pragma unroll
  for (int it = 0; it < 4; ++it) {
    const int c = it * 256 + tid;
    const int row = c >> 3, gch = (c & 7) ^ (row & 7);
    Ap[it] = A + (size_t)min(m0 + row, M - 1) * K + gch * 8;
    Wp[it] = W + (size_t)(n0 + row) * K + gch * 8;
    la[it] = Asm + c * 8;
    lb[it] = Bsm + c * 8;
  }

  floatx4 acc[4][4];
  #pragma unroll
  for (int i = 0; i < 4; ++i)
    #pragma unroll
    for (int j = 0; j < 4; ++j) { floatx4 z = {0.f, 0.f, 0.f, 0.f}; acc[i][j] = z; }

  const int ch0 = (quad ^ (l16 & 7)) << 3;
  const int ch1 = ((4 + quad) ^ (l16 & 7)) << 3;

  #pragma unroll 1
  for (int ko = 0; ko < K / 768; ++ko) {
    #pragma unroll
    for (int ki = 0; ki < 768; ki += 64) {
      __syncthreads();
      #pragma unroll
      for (int it = 0; it < 4; ++it) GLD16(Ap[it] + ki, la[it]);
      #pragma unroll
      for (int it = 0; it < 4; ++it) GLD16(Wp[it] + ki, lb[it]);
      __syncthreads();
      #pragma unroll
      for (int kk = 0; kk < 2; ++kk) {
        const int ch = kk ? ch1 : ch0;
        bf16x8 a[4], b[4];
        #pragma unroll
        for (int i = 0; i < 4; ++i) a[i] = *(const bf16x8*)&Asm[(wm * 64 + i * 16 + l16) * 64 + ch];
        #pragma unroll
        for (int j = 0; j < 4; ++j) b[j] = *(const bf16x8*)&Bsm[(wn * 64 + j * 16 + l16) * 64 + ch];
        #pragma unroll
        for (int i = 0; i < 4; ++i)
          #pragma unroll
          for (int j = 0; j < 4; ++j)
            acc[i][j] = __builtin_amdgcn_mfma_f32_16x16x32_bf16(b[j], a[i], acc[i][j], 0, 0, 0);
      }
    }
    if (K > 768) {
      #pragma unroll
      for (int it = 0; it < 4; ++it) { Ap[it] += 768; Wp[it] += 768; }
    }
  }

  #pragma unroll
  for (int j = 0; j < 4; ++j) {
    const float4 b4 = *(const float4*)(bias + n0 + wn * 64 + j * 16 + quad * 4);
    #pragma unroll
    for (int i = 0; i < 4; ++i) {
      acc[i][j][0] += b4.x; acc[i][j][1] += b4.y; acc[i][j][2] += b4.z; acc[i][j][3] += b4.w;
    }
  }
  if constexpr (EPI == 2) {
    #pragma unroll
    for (int i = 0; i < 4; ++i)
      #pragma unroll
      for (int j = 0; j < 4; ++j)
        #pragma unroll
        for (int r = 0; r < 4; ++r) {
          const float v = acc[i][j][r];
          acc[i][j][r] = v / (1.0f + exp2f(-2.3022221f * (v + 0.044715f * v * v * v)));
        }
  }
  __syncthreads();
  u16* Ep = SM + wave * 2304;
  #pragma unroll
  for (int h = 0; h < 2; ++h) {
    #pragma unroll
    for (int i2 = 0; i2 < 2; ++i2) {
      const int i = h * 2 + i2;
      #pragma unroll
      for (int j = 0; j < 4; ++j) {
        uint2 w;
        w.x = pk_bf16(acc[i][j][0], acc[i][j][1]);
        w.y = pk_bf16(acc[i][j][2], acc[i][j][3]);
        *(uint2*)&Ep[(i2 * 16 + l16) * 72 + j * 16 + quad * 4] = w;
      }
    }
    #pragma unroll
    for (int s = 0; s < 4; ++s) {
      const int lrow = s * 8 + (lane >> 3);
      const int gm = m0 + wm * 64 + h * 32 + lrow;
      const int gn = n0 + wn * 64 + (lane & 7) * 8;
      uint4 lv = *(const uint4*)&Ep[lrow * 72 + (lane & 7) * 8];
      if constexpr (EPI == 1 || EPI == 3) {
        const uint4 rv = *(const uint4*)(res + (size_t)min(gm, M - 1) * N + gn);
        const unsigned* lp = &lv.x; const unsigned* rp = &rv.x;
        uint4 ov; unsigned* op = &ov.x;
        #pragma unroll
        for (int d = 0; d < 4; ++d) {
          const float a0 = bf2f((u16)(lp[d] & 0xffffu)) + bf2f((u16)(rp[d] & 0xffffu));
          const float a1 = bf2f((u16)(lp[d] >> 16)) + bf2f((u16)(rp[d] >> 16));
          op[d] = pk_bf16(a0, a1);
        }
        lv = ov;
      }
      if (gm < M) *(uint4*)(out + (size_t)gm * N + gn) = lv;
    }
  }
}

// ---- 128x128 GEMM, 2 waves (128x64/wave, acc[8][4]) — wide-grid GEMM (qkv) ----
template<int EPI, int K, int NB>
__global__ __launch_bounds__(128, 2) void gemmw(
    const u16* __restrict__ A, const u16* __restrict__ W, const float* __restrict__ bias,
    const u16* __restrict__ res, u16* __restrict__ out, int M) {
  constexpr int N = NB * 128;
  __shared__ u16 SM[16384];            // A[128][64] @0, B[128][64] @8192 (u16)
  u16* Asm = SM;
  u16* Bsm = SM + 8192;
  const int tid = threadIdx.x, wave = tid >> 6, lane = tid & 63, quad = lane >> 4, l16 = lane & 15;
  const int lin = blockIdx.x;
  constexpr int FULL = 64 * NB;
  int mb, nb;
  if (lin < FULL) { const int g = lin / (8 * NB); const int r = lin - g * 8 * NB; mb = g * 8 + (r & 7); nb = r >> 3; }
  else { mb = 64; nb = lin - FULL; }
  const int m0 = mb * 128, n0 = nb * 128;

  const u16* Ap[8]; const u16* Wp[8];
  #pragma unroll
  for (int it = 0; it < 8; ++it) {
    const int row = it * 16 + (tid >> 3);
    const int gch = (tid & 7) ^ (row & 7);
    Ap[it] = A + (size_t)min(m0 + row, M - 1) * K + gch * 8;
    Wp[it] = W + (size_t)(n0 + row) * K + gch * 8;
  }

  floatx4 acc[8][4];
  #pragma unroll
  for (int i = 0; i < 8; ++i)
    #pragma unroll
    for (int j = 0; j < 4; ++j) { floatx4 z = {0.f, 0.f, 0.f, 0.f}; acc[i][j] = z; }

  const int ch0 = (quad ^ (l16 & 7)) << 3;
  const int ch1 = ((4 + quad) ^ (l16 & 7)) << 3;

  #pragma unroll 1
  for (int ko = 0; ko < K / 768; ++ko) {
    #pragma unroll
    for (int ki = 0; ki < 768; ki += 64) {
      __syncthreads();
      #pragma unroll
      for (int it = 0; it < 8; ++it) GLD16(Ap[it] + ki, (char*)SM + (it * 128 + tid) * 16);
      #pragma unroll
      for (int it = 0; it < 8; ++it) GLD16(Wp[it] + ki, (char*)SM + 16384 + (it * 128 + tid) * 16);
      __syncthreads();
      #pragma unroll
      for (int kk = 0; kk < 2; ++kk) {
        const int ch = kk ? ch1 : ch0;
        bf16x8 a[8], b[4];
        #pragma unroll
        for (int i = 0; i < 8; ++i) a[i] = *(const bf16x8*)&Asm[(i * 16 + l16) * 64 + ch];
        #pragma unroll
        for (int j = 0; j < 4; ++j) b[j] = *(const bf16x8*)&Bsm[(wave * 64 + j * 16 + l16) * 64 + ch];
        #pragma unroll
        for (int i = 0; i < 8; ++i)
          #pragma unroll
          for (int j = 0; j < 4; ++j)
            acc[i][j] = __builtin_amdgcn_mfma_f32_16x16x32_bf16(b[j], a[i], acc[i][j], 0, 0, 0);
      }
    }
    if (K > 768) {
      #pragma unroll
      for (int it = 0; it < 8; ++it) { Ap[it] += 768; Wp[it] += 768; }
    }
  }

  #pragma unroll
  for (int j = 0; j < 4; ++j) {
    const float4 b4 = *(const float4*)(bias + n0 + wave * 64 + j * 16 + quad * 4);
    #pragma unroll
    for (int i = 0; i < 8; ++i) {
      acc[i][j][0] += b4.x; acc[i][j][1] += b4.y; acc[i][j][2] += b4.z; acc[i][j][3] += b4.w;
    }
  }
  if constexpr (EPI == 2) {
    #pragma unroll
    for (int i = 0; i < 8; ++i)
      #pragma unroll
      for (int j = 0; j < 4; ++j)
        #pragma unroll
        for (int r = 0; r < 4; ++r) {
          const float v = acc[i][j][r];
          acc[i][j][r] = v / (1.0f + exp2f(-2.3022221f * (v + 0.044715f * v * v * v)));
        }
  }
  __syncthreads();
  u16* Ep = SM + wave * 2304;
  #pragma unroll
  for (int g = 0; g < 4; ++g) {
    #pragma unroll
    for (int i2 = 0; i2 < 2; ++i2) {
      const int i = g * 2 + i2;
      #pragma unroll
      for (int j = 0; j < 4; ++j) {
        uint2 w;
        w.x = pk_bf16(acc[i][j][0], acc[i][j][1]);
        w.y = pk_bf16(acc[i][j][2], acc[i][j][3]);
        *(uint2*)&Ep[(i2 * 16 + l16) * 72 + j * 16 + quad * 4] = w;
      }
    }
    #pragma unroll
    for (int s = 0; s < 4; ++s) {
      const int lrow = s * 8 + (lane >> 3);
      const int gm = m0 + g * 32 + lrow;
      const int gn = n0 + wave * 64 + (lane & 7) * 8;
      uint4 lv = *(const uint4*)&Ep[lrow * 72 + (lane & 7) * 8];
      if constexpr (EPI == 1 || EPI == 3) {
        const uint4 rv = *(const uint4*)(res + (size_t)min(gm, M - 1) * N + gn);
        const unsigned* lp = &lv.x; const unsigned* rp = &rv.x;
        uint4 ov; unsigned* op = &ov.x;
        #pragma unroll
        for (int d = 0; d < 4; ++d) {
          const float a0 = bf2f((u16)(lp[d] & 0xffffu)) + bf2f((u16)(rp[d] & 0xffffu));
          const float a1 = bf2f((u16)(lp[d] >> 16)) + bf2f((u16)(rp[d] >> 16));
          op[d] = pk_bf16(a0, a1);
        }
        lv = ov;
      }
      if (gm < M) *(uint4*)(out + (size_t)gm * N + gn) = lv;
    }
  }
}

// ---- v-section of qkv (strided) -> vt (bh, dh:64, s:1088) ----
__global__ __launch_bounds__(256) void vtrans(const u16* __restrict__ qkv, u16* __restrict__ vt) {
  __shared__ u16 t[32][33];
  const int bh = blockIdx.x, st = blockIdx.y, dt = blockIdx.z;
  const int bq = bh / NH, hh = bh % NH;
  u16* vd = vt + (size_t)bh * 64 * SQP;
  const int i = threadIdx.x, jj = threadIdx.y;
  #pragma unroll
  for (int kk = 0; kk < 4; ++kk) {
    int j = jj + kk * 8;   // j: s-local, i: d-local
    t[j][i] = qkv[(size_t)(bq * SQ + st * 32 + j) * 2304 + 1536 + hh * 64 + dt * 32 + i];
  }
  __syncthreads();
  #pragma unroll
  for (int kk = 0; kk < 4; ++kk) {
    int j = jj + kk * 8;   // j: d-local, i: s-local
    vd[(size_t)(dt * 32 + j) * SQP + st * 32 + i] = t[i][j];
  }
}

// ---- flash attention v3: 64 queries/block, Q direct-to-register, 25.25KB LDS ----
__global__ __launch_bounds__(256) void attn_flash(
    const u16* __restrict__ qkv, const u16* __restrict__ vt, u16* __restrict__ out) {
  const int bh = blockIdx.x, qt = blockIdx.y;   // bh fast: head slabs stay L2-resident
  const int b = bh / NH, h = bh % NH;
  const int tid = threadIdx.x, wave = tid >> 6, lane = tid & 63, quad = lane >> 4, l16 = lane & 15;
  __shared__ u16 Ks[4096], VTs[4096];  // [64][64], chunk q^(row&7) swizzle
  __shared__ u16 Ps[64 * 72];          // P[query][key], +8 pad
  const int q0 = qt * 64;
  const u16* qk = qkv + (size_t)b * SQ * 2304 + h * 64;
  const u16* vslab = vt + (size_t)bh * 64 * SQP;
  const int r0 = tid >> 3,         q0c = (tid & 7) ^ (r0 & 7);
  const int r1 = (tid + 256) >> 3, q1c = (tid & 7) ^ (r1 & 7);
  u16* L0K = Ks + wave * 512;  u16* L1K = Ks + 2048 + wave * 512;
  u16* L0V = VTs + wave * 512; u16* L1V = VTs + 2048 + wave * 512;

  const int qrow = wave * 16 + l16;
  // Q A-fragments straight from global (swizzle cancels: needed global chunk = quad / 4+quad)
  const bf16x8 qf0 = *(const bf16x8*)&qk[(size_t)(q0 + qrow) * 2304 + quad * 8];
  const bf16x8 qf1 = *(const bf16x8*)&qk[(size_t)(q0 + qrow) * 2304 + (4 + quad) * 8];

  floatx4 Oa[4];
  #pragma unroll
  for (int nt = 0; nt < 4; ++nt) { floatx4 z = {0.f, 0.f, 0.f, 0.f}; Oa[nt] = z; }
  float l_acc = 0.f;
  const bool qfeat = (q0 + qrow >= 5);

  for (int t = 0; t < 17; ++t) {
    const int k0 = t * 64;
    __syncthreads();
    GLD16(qk + 768 + (size_t)(k0 + r0) * 2304 + q0c * 8, L0K);
    GLD16(qk + 768 + (size_t)(k0 + r1) * 2304 + q1c * 8, L1K);
    GLD16(vslab + (size_t)r0 * SQP + k0 + q0c * 8, L0V);
    GLD16(vslab + (size_t)r1 * SQP + k0 + q1c * 8, L1V);
    __syncthreads();  // drains vmcnt -> K/V tiles valid

    // S^T = K·Q^T : C[key = mt*16+quad*4+r][query = wave*16+l16]; pre-scaled
    floatx4 st[4];
    #pragma unroll
    for (int mt = 0; mt < 4; ++mt) { floatx4 z = {0.f, 0.f, 0.f, 0.f}; st[mt] = z; }
    #pragma unroll
    for (int kk = 0; kk < 2; ++kk) {
      const bf16x8 qf = kk ? qf1 : qf0;
      #pragma unroll
      for (int mt = 0; mt < 4; ++mt) {
        const int krow = mt * 16 + l16;
        bf16x8 kf = *(const bf16x8*)&Ks[krow * 64 + (((kk * 4 + quad) ^ (krow & 7)) << 3)];
        st[mt] = __builtin_amdgcn_mfma_f32_16x16x32_bf16(kf, qf, st[mt], 0, 0, 0);
      }
    }

    // softmax numerator; masks only on edge tiles
    if (t == 16) {
      // keys 1024..1087: valid only mt==0 && quad*4+r < 5
      float p[4];
      #pragma unroll
      for (int r = 0; r < 4; ++r) {
        float pv = exp2f(st[0][r]);
        p[r] = (quad * 4 + r < 5) ? pv : 0.f;
      }
      l_acc += (p[0] + p[1]) + (p[2] + p[3]);
      uint2 w;
      w.x = pk_bf16(p[0], p[1]);
      w.y = pk_bf16(p[2], p[3]);
      *(uint2*)&Ps[qrow * 72 + quad * 4] = w;
      const uint2 zz = {0u, 0u};
      #pragma unroll
      for (int mt = 1; mt < 4; ++mt) *(uint2*)&Ps[qrow * 72 + mt * 16 + quad * 4] = zz;
    } else if (t == 0) {
      #pragma unroll
      for (int mt = 0; mt < 4; ++mt) {
        float p[4];
        #pragma unroll
        for (int r = 0; r < 4; ++r) {
          float pv = exp2f(st[mt][r]);
          if (mt == 0) pv = (qfeat && (quad * 4 + r < 5)) ? 0.f : pv;
          p[r] = pv;
        }
        l_acc += (p[0] + p[1]) + (p[2] + p[3]);
        uint2 w;
        w.x = pk_bf16(p[0], p[1]);
        w.y = pk_bf16(p[2], p[3]);
        *(uint2*)&Ps[qrow * 72 + mt * 16 + quad * 4] = w;
      }
    } else {
      #pragma unroll
      for (int mt = 0; mt < 4; ++mt) {
        float p[4];
        #pragma unroll
        for (int r = 0; r < 4; ++r) p[r] = exp2f(st[mt][r]);
        l_acc += (p[0] + p[1]) + (p[2] + p[3]);
        uint2 w;
        w.x = pk_bf16(p[0], p[1]);
        w.y = pk_bf16(p[2], p[3]);
        *(uint2*)&Ps[qrow * 72 + mt * 16 + quad * 4] = w;
      }
    }

    // O += P·V  (per-wave P rows: no barrier). t==16: kk=1 half of P is all zero.
    auto pv_step = [&](int kk) {
      bf16x8 pf = *(const bf16x8*)&Ps[qrow * 72 + kk * 32 + quad * 8];
      #pragma unroll
      for (int nt = 0; nt < 4; ++nt) {
        const int brow = nt * 16 + l16;
        bf16x8 bb = *(const bf16x8*)&VTs[brow * 64 + (((kk * 4 + quad) ^ (brow & 7)) << 3)];
        Oa[nt] = __builtin_amdgcn_mfma_f32_16x16x32_bf16(pf, bb, Oa[nt], 0, 0, 0);
      }
    };
    pv_step(0);
    if (t != 16) pv_step(1);
  }

  float lt = l_acc;
  lt += __shfl_xor(lt, 16);
  lt += __shfl_xor(lt, 32);
  lt = fmaxf(lt, 1e-30f);
  #pragma unroll
  for (int nt = 0; nt < 4; ++nt)
    #pragma unroll
    for (int r = 0; r < 4; ++r) {
      const int qo = quad * 4 + r;
      const float lr = __shfl(lt, (lane & 48) | qo);
      const int qg2 = q0 + wave * 16 + qo;
      if (qg2 < SQ)
        out[((size_t)b * SQ + qg2) * DM + h * 64 + nt * 16 + l16] = f2bf(Oa[nt][r] / lr);
    }
}

// ---- yfin feature rows -> d_out fp32 (blocks 0..6143) + token outputs (blocks 6144..) ----
__global__ __launch_bounds__(256) void transpose_out(const u16* __restrict__ yf, float* __restrict__ out) {
  const int bx = blockIdx.x;
  const int tid = threadIdx.x;
  if (bx >= 6144) {                    // context + register token outputs
    const int idx = (bx - 6144) * 256 + tid;
    if (idx >= 8 * 5 * DM) return;
    const int b = idx / (5 * DM);
    const int r = idx % (5 * DM);
    const int s = r / DM, c = r % DM;
    const float v = bf2f(yf[((size_t)b * SQ + s) * DM + c]);
    if (s == 0) out[(size_t)6291456 + (size_t)b * DM + c] = v;
    else out[(size_t)6291456 + 6144 + ((size_t)b * 4 + (s - 1)) * DM + c] = v;
    return;
  }
  __shared__ u16 tile[32][33];
  const int b = bx / 768, rr = bx % 768, nt = rr / 24, ct = rr % 24;
  const int i = tid & 31, jj = tid >> 5;
  #pragma unroll
  for (int kk = 0; kk < 4; ++kk) {
    int j = jj + kk * 8;
    tile[j][i] = yf[((size_t)b * SQ + 5 + nt * 32 + j) * DM + ct * 32 + i];
  }
  __syncthreads();
  #pragma unroll
  for (int kk = 0; kk < 4; ++kk) {
    int j = jj + kk * 8;
    out[((size_t)b * 768 + ct * 32 + j) * 1024 + nt * 32 + i] = bf2f(tile[i][j]);
  }
}

extern "C" void kernel_launch(void* const* d_in, const int* in_sizes, int n_in,
                              void* d_out, int out_size, void* d_ws, size_t ws_size,
                              hipStream_t stream) {
  const float* x    = (const float*)d_in[0];
  const float* ctx  = (const float*)d_in[1];
  const float* regt = (const float*)d_in[2];
  const float* wqkv = (const float*)d_in[3];
  const float* bqkv = (const float*)d_in[4];
  const float* wout = (const float*)d_in[5];
  const float* bout = (const float*)d_in[6];
  const float* ln1s = (const float*)d_in[7];
  const float* ln1b = (const float*)d_in[8];
  const float* ln2s = (const float*)d_in[9];
  const float* ln2b = (const float*)d_in[10];
  const float* w1   = (const float*)d_in[11];
  const float* b1   = (const float*)d_in[12];
  const float* w2   = (const float*)d_in[13];
  const float* b2   = (const float*)d_in[14];

  char* ws = (char*)d_ws;
  u16* wb_all = (u16*)(ws + OFF_WQKV);
  u16* wqkv_b = (u16*)(ws + OFF_WQKV);
  u16* wout_b = (u16*)(ws + OFF_WOUT);
  u16* w1_b   = (u16*)(ws + OFF_W1);
  u16* w2_b   = (u16*)(ws + OFF_W2);
  u16* xwt    = (u16*)(ws + OFF_XWT);
  u16* qkv    = (u16*)(ws + OFF_QKV);   // 8320 x 2304 bf16
  u16* vtb    = (u16*)(ws + OFF_VT);
  u16* yb     = (u16*)(ws + OFF_Y);
  float* bqs  = (float*)(ws + OFF_BQ);
  u16* attnb  = (u16*)(ws + OFF_XF);    // scratch region
  u16* ynorm  = (u16*)(ws + OFF_XF);    // attnb dead after out_proj
  u16* h1     = (u16*)(ws + OFF_QKV);   // qkv/vt dead after attention
  u16* yfin   = (u16*)(ws + OFF_XWT);   // xwt dead after out_proj residual
  float* outp = (float*)d_out;

  convw_all   <<<6915, 256, 0, stream>>>(wqkv, wout, w1, w2, bqkv, wb_all, bqs);
  ln1_fused   <<<296, 256, 0, stream>>>(x, ctx, regt, ln1s, ln1b, xwt);
  gemmw<0, 768, 18><<<65 * 18, 128, 0, stream>>>(xwt, wqkv_b, bqs, nullptr, qkv, 8232);
  vtrans      <<<dim3(96, 34, 2), dim3(32, 8), 0, stream>>>(qkv, vtb);
  attn_flash  <<<dim3(96, 17), 256, 0, stream>>>(qkv, vtb, attnb);
  gemmk<1, 768, 6><<<65 * 6, 256, 0, stream>>>(attnb, wout_b, bout, xwt, yb, 8232);
  ln2k        <<<2058, 256, 0, stream>>>(yb, ln2s, ln2b, ynorm);
  gemmk<2, 768, 24><<<65 * 24, 256, 0, stream>>>(ynorm, w1_b, b1, nullptr, h1, 8232);
  gemmk<3, 3072, 6><<<65 * 6, 256, 0, stream>>>(h1, w2_b, b2, yb, yfin, 8232);
  transpose_out<<<6264, 256, 0, stream>>>(yfin, outp);
}

// Round 19
// 385.568 us; speedup vs baseline: 1.0047x; 1.0047x over previous
//
#include <hip/hip_runtime.h>
#include <hip/hip_bf16.h>
#include <cmath>

typedef unsigned short u16;
typedef __bf16 bf16x8 __attribute__((ext_vector_type(8)));
typedef float floatx4 __attribute__((ext_vector_type(4)));

#define SQ 1029
#define DM 768
#define NH 12
#define SQP 1088   // 17*64 tile coverage for attention
#define SSC 0.18033688011112042f   // 0.125 * log2(e), folded into q

// async global->LDS, 16B per lane; LDS dest = wave-uniform base + lane*16
#define GLD16(gp, lp) __builtin_amdgcn_global_load_lds( \
    (const __attribute__((address_space(1))) unsigned int*)(gp), \
    (__attribute__((address_space(3))) unsigned int*)(lp), 16, 0, 0)

// ---- workspace layout (bytes) ----
#define OFF_WQKV ((size_t)0)
#define OFF_WOUT ((size_t)3538944)
#define OFF_W1   ((size_t)4718592)
#define OFF_W2   ((size_t)9437184)
#define OFF_XF   ((size_t)14155776)
#define OFF_XWT  ((size_t)26800128)
#define OFF_QKV  ((size_t)39444480)
#define OFF_VT   ((size_t)77783040)
#define OFF_Y    ((size_t)91152384)
#define OFF_BQ   ((size_t)103796736)   // 2304 fp32 scaled qkv bias

__device__ __forceinline__ float bf2f(u16 u) {
  unsigned int x = ((unsigned int)u) << 16;
  float f; __builtin_memcpy(&f, &x, 4); return f;
}
__device__ __forceinline__ u16 f2bf(float f) {
  unsigned int x; __builtin_memcpy(&x, &f, 4);
  x = (x + 0x7fffu + ((x >> 16) & 1u)) >> 16;   // RNE
  return (u16)x;
}
__device__ __forceinline__ unsigned int pk_bf16(float a, float b) {
  __hip_bfloat162 h = __float22bfloat162_rn(make_float2(a, b));
  unsigned int u; __builtin_memcpy(&u, &h, 4); return u;
}

__device__ __forceinline__ void blockReduce2(float& s1, float& s2) {
  #pragma unroll
  for (int o = 32; o > 0; o >>= 1) { s1 += __shfl_xor(s1, o); s2 += __shfl_xor(s2, o); }
  __shared__ float t1[4], t2[4];
  const int w = threadIdx.x >> 6;
  if ((threadIdx.x & 63) == 0) { t1[w] = s1; t2[w] = s2; }
  __syncthreads();
  s1 = t1[0] + t1[1] + t1[2] + t1[3];
  s2 = t2[0] + t2[1] + t2[2] + t2[3];
}

// ---- all fp32 weights -> bf16 (q rows pre-scaled) + scaled qkv bias, one launch ----
__global__ __launch_bounds__(256) void convw_all(
    const float* __restrict__ a, const float* __restrict__ b,
    const float* __restrict__ c, const float* __restrict__ d,
    const float* __restrict__ bq, u16* __restrict__ dst, float* __restrict__ bqs) {
  int i = blockIdx.x * 256 + threadIdx.x;
  if (i >= 1770048) return;
  if (i >= 1769472) {                      // qkv bias tail: 576 float4 = 2304 fp32
    const int off = i - 1769472;
    float4 v = ((const float4*)bq)[off];
    if (off < 192) { v.x *= SSC; v.y *= SSC; v.z *= SSC; v.w *= SSC; }  // q entries
    ((float4*)bqs)[off] = v;
    return;
  }
  const float* src; int off;
  if (i < 442368)       { src = a; off = i; }
  else if (i < 589824)  { src = b; off = i - 442368; }
  else if (i < 1179648) { src = c; off = i - 589824; }
  else                  { src = d; off = i - 1179648; }
  float4 v = ((const float4*)src)[off];
  if (i < 147456) { v.x *= SSC; v.y *= SSC; v.z *= SSC; v.w *= SSC; }  // q rows of wqkv
  ushort4 o; o.x = f2bf(v.x); o.y = f2bf(v.y); o.z = f2bf(v.z); o.w = f2bf(v.w);
  ((ushort4*)dst)[i] = o;
}

// ---- LN1: feature rows (fused transpose, blocks 0..255) + token rows (blocks 256..295) ----
__global__ __launch_bounds__(256) void ln1_fused(
    const float* __restrict__ x, const float* __restrict__ ctx, const float* __restrict__ regt,
    const float* __restrict__ g, const float* __restrict__ be, u16* __restrict__ xwt) {
  const int bx = blockIdx.x;
  const int tid = threadIdx.x;
  if (bx >= 256) {                     // token rows: tokens+PE, LN1
    const int row = bx - 256;          // 0..39
    const int b = row / 5, s = row % 5;
    float v[3];
    #pragma unroll
    for (int i = 0; i < 3; ++i) {
      const int c = tid + i * 256;
      float tok = (s == 0) ? ctx[c] : regt[(s - 1) * DM + c];
      float e = (float)(2 * (c / 2)) * (1.0f / 768.0f);
      float ang = (float)s / powf(10000.0f, e);
      v[i] = tok + ((c & 1) ? cosf(ang) : sinf(ang));
    }
    float s1 = v[0] + v[1] + v[2];
    float s2 = v[0] * v[0] + v[1] * v[1] + v[2] * v[2];
    blockReduce2(s1, s2);
    const float mean = s1 * (1.0f / 768.0f);
    const float var = s2 * (1.0f / 768.0f) - mean * mean;
    const float rs = rsqrtf(fmaxf(var, 0.0f) + 1e-5f);
    #pragma unroll
    for (int i = 0; i < 3; ++i) {
      const int c = tid + i * 256;
      xwt[((size_t)b * SQ + s) * DM + c] = f2bf((v[i] - mean) * rs * g[c] + be[c]);
    }
    return;
  }
  // feature rows: x fp32 (8,768,1024) -> xwt rows 5.. ; 4 waves x 8 rows
  __shared__ u16 XT[32][772];
  const int b = bx >> 5, st = bx & 31;
  const int i2 = tid & 15, cj = tid >> 4;
  const int n0 = st * 32;
  #pragma unroll 4
  for (int ct = 0; ct < 48; ++ct) {
    const int c = ct * 16 + cj;
    const float2 v = *(const float2*)&x[((size_t)b * 768 + c) * 1024 + n0 + i2 * 2];
    XT[i2 * 2][c]     = f2bf(v.x);
    XT[i2 * 2 + 1][c] = f2bf(v.y);
  }
  __syncthreads();
  const int wave = tid >> 6, lane = tid & 63;
  float gr[12], br[12];
  #pragma unroll
  for (int k = 0; k < 12; ++k) { gr[k] = g[lane + k * 64]; br[k] = be[lane + k * 64]; }
  #pragma unroll
  for (int rr = 0; rr < 8; ++rr) {
    const int row = wave * 8 + rr;
    float v[12];
    float s1 = 0.f, s2 = 0.f;
    #pragma unroll
    for (int k = 0; k < 12; ++k) {
      v[k] = bf2f(XT[row][lane + k * 64]);
      s1 += v[k]; s2 += v[k] * v[k];
    }
    #pragma unroll
    for (int o = 32; o > 0; o >>= 1) { s1 += __shfl_xor(s1, o); s2 += __shfl_xor(s2, o); }
    const float mean = s1 * (1.0f / 768.0f);
    const float var = s2 * (1.0f / 768.0f) - mean * mean;
    const float rs = rsqrtf(fmaxf(var, 0.0f) + 1e-5f);
    u16* dst = xwt + ((size_t)b * SQ + 5 + n0 + row) * DM;
    #pragma unroll
    for (int k = 0; k < 12; ++k)
      dst[lane + k * 64] = f2bf((v[k] - mean) * rs * gr[k] + br[k]);
  }
}

// ---- LN2 vectorized: wave-per-row, ushort4 loads (8B/lane), uint2 stores ----
__global__ __launch_bounds__(256) void ln2k(
    const u16* __restrict__ y, const float* __restrict__ g, const float* __restrict__ be,
    u16* __restrict__ out) {
  const int row = blockIdx.x * 4 + (threadIdx.x >> 6);
  const int lane = threadIdx.x & 63;
  const u16* src = y + (size_t)row * DM;
  float v[12];
  float s1 = 0.f, s2 = 0.f;
  #pragma unroll
  for (int k = 0; k < 3; ++k) {
    const ushort4 u = *(const ushort4*)&src[k * 256 + lane * 4];
    const float a0 = bf2f(u.x), a1 = bf2f(u.y), a2 = bf2f(u.z), a3 = bf2f(u.w);
    v[k * 4 + 0] = a0; v[k * 4 + 1] = a1; v[k * 4 + 2] = a2; v[k * 4 + 3] = a3;
    s1 += (a0 + a1) + (a2 + a3);
    s2 += (a0 * a0 + a1 * a1) + (a2 * a2 + a3 * a3);
  }
  #pragma unroll
  for (int o = 32; o > 0; o >>= 1) { s1 += __shfl_xor(s1, o); s2 += __shfl_xor(s2, o); }
  const float mean = s1 * (1.0f / 768.0f);
  const float var = s2 * (1.0f / 768.0f) - mean * mean;
  const float rs = rsqrtf(fmaxf(var, 0.0f) + 1e-5f);
  u16* dst = out + (size_t)row * DM;
  #pragma unroll
  for (int k = 0; k < 3; ++k) {
    const float4 g4 = *(const float4*)&g[k * 256 + lane * 4];
    const float4 b4 = *(const float4*)&be[k * 256 + lane * 4];
    uint2 w;
    w.x = pk_bf16((v[k * 4 + 0] - mean) * rs * g4.x + b4.x,
                  (v[k * 4 + 1] - mean) * rs * g4.y + b4.y);
    w.y = pk_bf16((v[k * 4 + 2] - mean) * rs * g4.z + b4.z,
                  (v[k * 4 + 3] - mean) * rs * g4.w + b4.w);
    *(uint2*)&dst[k * 256 + lane * 4] = w;
  }
}

// ---- 128x128 GEMM, 4 waves (64x64/wave), BK=64 — proven baseline (out_proj, ffn1, ffn2) ----
template<int EPI, int K, int NB>
__global__ __launch_bounds__(256) void gemmk(
    const u16* __restrict__ A, const u16* __restrict__ W, const float* __restrict__ bias,
    const u16* __restrict__ res, u16* __restrict__ out, int M) {
  constexpr int N = NB * 128;
  __shared__ u16 SM[16384];
  u16* Asm = SM;
  u16* Bsm = SM + 8192;
  const int tid = threadIdx.x, wave = tid >> 6, lane = tid & 63, quad = lane >> 4, l16 = lane & 15;
  const int lin = blockIdx.x;
  constexpr int FULL = 64 * NB;
  int mb, nb;
  if (lin < FULL) { const int g = lin / (8 * NB); const int r = lin - g * 8 * NB; mb = g * 8 + (r & 7); nb = r >> 3; }
  else { mb = 64; nb = lin - FULL; }
  const int m0 = mb * 128, n0 = nb * 128;
  const int wm = wave & 1, wn = wave >> 1;

  const u16* Ap[4]; const u16* Wp[4]; u16* la[4]; u16* lb[4];
  #pragma unroll
  for (int it = 0; it < 4; ++it) {
    const int c = it * 256 + tid;
    const int row = c >> 3, gch = (c & 7) ^ (row & 7);
    Ap[it] = A + (size_t)min(m0 + row, M - 1) * K + gch * 8;
    Wp[it] = W + (size_t)(n0 + row) * K + gch * 8;
    la[it] = Asm + c * 8;
    lb[it] = Bsm + c * 8;
  }

  floatx4 acc[4][4];
  #pragma unroll
  for (int i = 0; i < 4; ++i)
    #pragma unroll
    for (int j = 0; j < 4; ++j) { floatx4 z = {0.f, 0.f, 0.f, 0.f}; acc[i][j] = z; }

  const int ch0 = (quad ^ (l16 & 7)) << 3;
  const int ch1 = ((4 + quad) ^ (l16 & 7)) << 3;

  #pragma unroll 1
  for (int ko = 0; ko < K / 768; ++ko) {
    #pragma unroll
    for (int ki = 0; ki < 768; ki += 64) {
      __syncthreads();
      #pragma unroll
      for (int it = 0; it < 4; ++it) GLD16(Ap[it] + ki, la[it]);
      #pragma unroll
      for (int it = 0; it < 4; ++it) GLD16(Wp[it] + ki, lb[it]);
      __syncthreads();
      #pragma unroll
      for (int kk = 0; kk < 2; ++kk) {
        const int ch = kk ? ch1 : ch0;
        bf16x8 a[4], b[4];
        #pragma unroll
        for (int i = 0; i < 4; ++i) a[i] = *(const bf16x8*)&Asm[(wm * 64 + i * 16 + l16) * 64 + ch];
        #pragma unroll
        for (int j = 0; j < 4; ++j) b[j] = *(const bf16x8*)&Bsm[(wn * 64 + j * 16 + l16) * 64 + ch];
        #pragma unroll
        for (int i = 0; i < 4; ++i)
          #pragma unroll
          for (int j = 0; j < 4; ++j)
            acc[i][j] = __builtin_amdgcn_mfma_f32_16x16x32_bf16(b[j], a[i], acc[i][j], 0, 0, 0);
      }
    }
    if (K > 768) {
      #pragma unroll
      for (int it = 0; it < 4; ++it) { Ap[it] += 768; Wp[it] += 768; }
    }
  }

  #pragma unroll
  for (int j = 0; j < 4; ++j) {
    const float4 b4 = *(const float4*)(bias + n0 + wn * 64 + j * 16 + quad * 4);
    #pragma unroll
    for (int i = 0; i < 4; ++i) {
      acc[i][j][0] += b4.x; acc[i][j][1] += b4.y; acc[i][j][2] += b4.z; acc[i][j][3] += b4.w;
    }
  }
  if constexpr (EPI == 2) {
    #pragma unroll
    for (int i = 0; i < 4; ++i)
      #pragma unroll
      for (int j = 0; j < 4; ++j)
        #pragma unroll
        for (int r = 0; r < 4; ++r) {
          const float v = acc[i][j][r];
          acc[i][j][r] = v / (1.0f + exp2f(-2.3022221f * (v + 0.044715f * v * v * v)));
        }
  }
  __syncthreads();
  u16* Ep = SM + wave * 2304;
  #pragma unroll
  for (int h = 0; h < 2; ++h) {
    #pragma unroll
    for (int i2 = 0; i2 < 2; ++i2) {
      const int i = h * 2 + i2;
      #pragma unroll
      for (int j = 0; j < 4; ++j) {
        uint2 w;
        w.x = pk_bf16(acc[i][j][0], acc[i][j][1]);
        w.y = pk_bf16(acc[i][j][2], acc[i][j][3]);
        *(uint2*)&Ep[(i2 * 16 + l16) * 72 + j * 16 + quad * 4] = w;
      }
    }
    #pragma unroll
    for (int s = 0; s < 4; ++s) {
      const int lrow = s * 8 + (lane >> 3);
      const int gm = m0 + wm * 64 + h * 32 + lrow;
      const int gn = n0 + wn * 64 + (lane & 7) * 8;
      uint4 lv = *(const uint4*)&Ep[lrow * 72 + (lane & 7) * 8];
      if constexpr (EPI == 1 || EPI == 3) {
        const uint4 rv = *(const uint4*)(res + (size_t)min(gm, M - 1) * N + gn);
        const unsigned* lp = &lv.x; const unsigned* rp = &rv.x;
        uint4 ov; unsigned* op = &ov.x;
        #pragma unroll
        for (int d = 0; d < 4; ++d) {
          const float a0 = bf2f((u16)(lp[d] & 0xffffu)) + bf2f((u16)(rp[d] & 0xffffu));
          const float a1 = bf2f((u16)(lp[d] >> 16)) + bf2f((u16)(rp[d] >> 16));
          op[d] = pk_bf16(a0, a1);
        }
        lv = ov;
      }
      if (gm < M) *(uint4*)(out + (size_t)gm * N + gn) = lv;
    }
  }
}

// ---- 128x128 GEMM, 2 waves (128x64/wave, acc[8][4]) — wide-grid GEMM (qkv) ----
template<int EPI, int K, int NB>
__global__ __launch_bounds__(128, 2) void gemmw(
    const u16* __restrict__ A, const u16* __restrict__ W, const float* __restrict__ bias,
    const u16* __restrict__ res, u16* __restrict__ out, int M) {
  constexpr int N = NB * 128;
  __shared__ u16 SM[16384];            // A[128][64] @0, B[128][64] @8192 (u16)
  u16* Asm = SM;
  u16* Bsm = SM + 8192;
  const int tid = threadIdx.x, wave = tid >> 6, lane = tid & 63, quad = lane >> 4, l16 = lane & 15;
  const int lin = blockIdx.x;
  constexpr int FULL = 64 * NB;
  int mb, nb;
  if (lin < FULL) { const int g = lin / (8 * NB); const int r = lin - g * 8 * NB; mb = g * 8 + (r & 7); nb = r >> 3; }
  else { mb = 64; nb = lin - FULL; }
  const int m0 = mb * 128, n0 = nb * 128;

  const u16* Ap[8]; const u16* Wp[8];
  #pragma unroll
  for (int it = 0; it < 8; ++it) {
    const int row = it * 16 + (tid >> 3);
    const int gch = (tid & 7) ^ (row & 7);
    Ap[it] = A + (size_t)min(m0 + row, M - 1) * K + gch * 8;
    Wp[it] = W + (size_t)(n0 + row) * K + gch * 8;
  }

  floatx4 acc[8][4];
  #pragma unroll
  for (int i = 0; i < 8; ++i)
    #pragma unroll
    for (int j = 0; j < 4; ++j) { floatx4 z = {0.f, 0.f, 0.f, 0.f}; acc[i][j] = z; }

  const int ch0 = (quad ^ (l16 & 7)) << 3;
  const int ch1 = ((4 + quad) ^ (l16 & 7)) << 3;

  #pragma unroll 1
  for (int ko = 0; ko < K / 768; ++ko) {
    #pragma unroll
    for (int ki = 0; ki < 768; ki += 64) {
      __syncthreads();
      #pragma unroll
      for (int it = 0; it < 8; ++it) GLD16(Ap[it] + ki, (char*)SM + (it * 128 + tid) * 16);
      #pragma unroll
      for (int it = 0; it < 8; ++it) GLD16(Wp[it] + ki, (char*)SM + 16384 + (it * 128 + tid) * 16);
      __syncthreads();
      #pragma unroll
      for (int kk = 0; kk < 2; ++kk) {
        const int ch = kk ? ch1 : ch0;
        bf16x8 a[8], b[4];
        #pragma unroll
        for (int i = 0; i < 8; ++i) a[i] = *(const bf16x8*)&Asm[(i * 16 + l16) * 64 + ch];
        #pragma unroll
        for (int j = 0; j < 4; ++j) b[j] = *(const bf16x8*)&Bsm[(wave * 64 + j * 16 + l16) * 64 + ch];
        #pragma unroll
        for (int i = 0; i < 8; ++i)
          #pragma unroll
          for (int j = 0; j < 4; ++j)
            acc[i][j] = __builtin_amdgcn_mfma_f32_16x16x32_bf16(b[j], a[i], acc[i][j], 0, 0, 0);
      }
    }
    if (K > 768) {
      #pragma unroll
      for (int it = 0; it < 8; ++it) { Ap[it] += 768; Wp[it] += 768; }
    }
  }

  #pragma unroll
  for (int j = 0; j < 4; ++j) {
    const float4 b4 = *(const float4*)(bias + n0 + wave * 64 + j * 16 + quad * 4);
    #pragma unroll
    for (int i = 0; i < 8; ++i) {
      acc[i][j][0] += b4.x; acc[i][j][1] += b4.y; acc[i][j][2] += b4.z; acc[i][j][3] += b4.w;
    }
  }
  if constexpr (EPI == 2) {
    #pragma unroll
    for (int i = 0; i < 8; ++i)
      #pragma unroll
      for (int j = 0; j < 4; ++j)
        #pragma unroll
        for (int r = 0; r < 4; ++r) {
          const float v = acc[i][j][r];
          acc[i][j][r] = v / (1.0f + exp2f(-2.3022221f * (v + 0.044715f * v * v * v)));
        }
  }
  __syncthreads();
  u16* Ep = SM + wave * 2304;
  #pragma unroll
  for (int g = 0; g < 4; ++g) {
    #pragma unroll
    for (int i2 = 0; i2 < 2; ++i2) {
      const int i = g * 2 + i2;
      #pragma unroll
      for (int j = 0; j < 4; ++j) {
        uint2 w;
        w.x = pk_bf16(acc[i][j][0], acc[i][j][1]);
        w.y = pk_bf16(acc[i][j][2], acc[i][j][3]);
        *(uint2*)&Ep[(i2 * 16 + l16) * 72 + j * 16 + quad * 4] = w;
      }
    }
    #pragma unroll
    for (int s = 0; s < 4; ++s) {
      const int lrow = s * 8 + (lane >> 3);
      const int gm = m0 + g * 32 + lrow;
      const int gn = n0 + wave * 64 + (lane & 7) * 8;
      uint4 lv = *(const uint4*)&Ep[lrow * 72 + (lane & 7) * 8];
      if constexpr (EPI == 1 || EPI == 3) {
        const uint4 rv = *(const uint4*)(res + (size_t)min(gm, M - 1) * N + gn);
        const unsigned* lp = &lv.x; const unsigned* rp = &rv.x;
        uint4 ov; unsigned* op = &ov.x;
        #pragma unroll
        for (int d = 0; d < 4; ++d) {
          const float a0 = bf2f((u16)(lp[d] & 0xffffu)) + bf2f((u16)(rp[d] & 0xffffu));
          const float a1 = bf2f((u16)(lp[d] >> 16)) + bf2f((u16)(rp[d] >> 16));
          op[d] = pk_bf16(a0, a1);
        }
        lv = ov;
      }
      if (gm < M) *(uint4*)(out + (size_t)gm * N + gn) = lv;
    }
  }
}

// ---- v-section of qkv (strided) -> vt (bh, dh:64, s:1088) ----
__global__ __launch_bounds__(256) void vtrans(const u16* __restrict__ qkv, u16* __restrict__ vt) {
  __shared__ u16 t[32][33];
  const int bh = blockIdx.x, st = blockIdx.y, dt = blockIdx.z;
  const int bq = bh / NH, hh = bh % NH;
  u16* vd = vt + (size_t)bh * 64 * SQP;
  const int i = threadIdx.x, jj = threadIdx.y;
  #pragma unroll
  for (int kk = 0; kk < 4; ++kk) {
    int j = jj + kk * 8;   // j: s-local, i: d-local
    t[j][i] = qkv[(size_t)(bq * SQ + st * 32 + j) * 2304 + 1536 + hh * 64 + dt * 32 + i];
  }
  __syncthreads();
  #pragma unroll
  for (int kk = 0; kk < 4; ++kk) {
    int j = jj + kk * 8;   // j: d-local, i: s-local
    vd[(size_t)(dt * 32 + j) * SQP + st * 32 + i] = t[i][j];
  }
}

// ---- flash attention v3: 64 queries/block, Q direct-to-register, 25.25KB LDS ----
__global__ __launch_bounds__(256) void attn_flash(
    const u16* __restrict__ qkv, const u16* __restrict__ vt, u16* __restrict__ out) {
  const int bh = blockIdx.x, qt = blockIdx.y;   // bh fast: head slabs stay L2-resident
  const int b = bh / NH, h = bh % NH;
  const int tid = threadIdx.x, wave = tid >> 6, lane = tid & 63, quad = lane >> 4, l16 = lane & 15;
  __shared__ u16 Ks[4096], VTs[4096];  // [64][64], chunk q^(row&7) swizzle
  __shared__ u16 Ps[64 * 72];          // P[query][key], +8 pad
  const int q0 = qt * 64;
  const u16* qk = qkv + (size_t)b * SQ * 2304 + h * 64;
  const u16* vslab = vt + (size_t)bh * 64 * SQP;
  const int r0 = tid >> 3,         q0c = (tid & 7) ^ (r0 & 7);
  const int r1 = (tid + 256) >> 3, q1c = (tid & 7) ^ (r1 & 7);
  u16* L0K = Ks + wave * 512;  u16* L1K = Ks + 2048 + wave * 512;
  u16* L0V = VTs + wave * 512; u16* L1V = VTs + 2048 + wave * 512;

  const int qrow = wave * 16 + l16;
  // Q A-fragments straight from global (swizzle cancels: needed global chunk = quad / 4+quad)
  const bf16x8 qf0 = *(const bf16x8*)&qk[(size_t)(q0 + qrow) * 2304 + quad * 8];
  const bf16x8 qf1 = *(const bf16x8*)&qk[(size_t)(q0 + qrow) * 2304 + (4 + quad) * 8];

  floatx4 Oa[4];
  #pragma unroll
  for (int nt = 0; nt < 4; ++nt) { floatx4 z = {0.f, 0.f, 0.f, 0.f}; Oa[nt] = z; }
  float l_acc = 0.f;
  const bool qfeat = (q0 + qrow >= 5);

  for (int t = 0; t < 17; ++t) {
    const int k0 = t * 64;
    __syncthreads();
    GLD16(qk + 768 + (size_t)(k0 + r0) * 2304 + q0c * 8, L0K);
    GLD16(qk + 768 + (size_t)(k0 + r1) * 2304 + q1c * 8, L1K);
    GLD16(vslab + (size_t)r0 * SQP + k0 + q0c * 8, L0V);
    GLD16(vslab + (size_t)r1 * SQP + k0 + q1c * 8, L1V);
    __syncthreads();  // drains vmcnt -> K/V tiles valid

    // S^T = K·Q^T : C[key = mt*16+quad*4+r][query = wave*16+l16]; pre-scaled
    floatx4 st[4];
    #pragma unroll
    for (int mt = 0; mt < 4; ++mt) { floatx4 z = {0.f, 0.f, 0.f, 0.f}; st[mt] = z; }
    #pragma unroll
    for (int kk = 0; kk < 2; ++kk) {
      const bf16x8 qf = kk ? qf1 : qf0;
      #pragma unroll
      for (int mt = 0; mt < 4; ++mt) {
        const int krow = mt * 16 + l16;
        bf16x8 kf = *(const bf16x8*)&Ks[krow * 64 + (((kk * 4 + quad) ^ (krow & 7)) << 3)];
        st[mt] = __builtin_amdgcn_mfma_f32_16x16x32_bf16(kf, qf, st[mt], 0, 0, 0);
      }
    }

    // softmax numerator; masks only on edge tiles
    if (t == 16) {
      // keys 1024..1087: valid only mt==0 && quad*4+r < 5
      float p[4];
      #pragma unroll
      for (int r = 0; r < 4; ++r) {
        float pv = exp2f(st[0][r]);
        p[r] = (quad * 4 + r < 5) ? pv : 0.f;
      }
      l_acc += (p[0] + p[1]) + (p[2] + p[3]);
      uint2 w;
      w.x = pk_bf16(p[0], p[1]);
      w.y = pk_bf16(p[2], p[3]);
      *(uint2*)&Ps[qrow * 72 + quad * 4] = w;
      const uint2 zz = {0u, 0u};
      #pragma unroll
      for (int mt = 1; mt < 4; ++mt) *(uint2*)&Ps[qrow * 72 + mt * 16 + quad * 4] = zz;
    } else if (t == 0) {
      #pragma unroll
      for (int mt = 0; mt < 4; ++mt) {
        float p[4];
        #pragma unroll
        for (int r = 0; r < 4; ++r) {
          float pv = exp2f(st[mt][r]);
          if (mt == 0) pv = (qfeat && (quad * 4 + r < 5)) ? 0.f : pv;
          p[r] = pv;
        }
        l_acc += (p[0] + p[1]) + (p[2] + p[3]);
        uint2 w;
        w.x = pk_bf16(p[0], p[1]);
        w.y = pk_bf16(p[2], p[3]);
        *(uint2*)&Ps[qrow * 72 + mt * 16 + quad * 4] = w;
      }
    } else {
      #pragma unroll
      for (int mt = 0; mt < 4; ++mt) {
        float p[4];
        #pragma unroll
        for (int r = 0; r < 4; ++r) p[r] = exp2f(st[mt][r]);
        l_acc += (p[0] + p[1]) + (p[2] + p[3]);
        uint2 w;
        w.x = pk_bf16(p[0], p[1]);
        w.y = pk_bf16(p[2], p[3]);
        *(uint2*)&Ps[qrow * 72 + mt * 16 + quad * 4] = w;
      }
    }

    // O += P·V  (per-wave P rows: no barrier). t==16: kk=1 half of P is all zero.
    auto pv_step = [&](int kk) {
      bf16x8 pf = *(const bf16x8*)&Ps[qrow * 72 + kk * 32 + quad * 8];
      #pragma unroll
      for (int nt = 0; nt < 4; ++nt) {
        const int brow = nt * 16 + l16;
        bf16x8 bb = *(const bf16x8*)&VTs[brow * 64 + (((kk * 4 + quad) ^ (brow & 7)) << 3)];
        Oa[nt] = __builtin_amdgcn_mfma_f32_16x16x32_bf16(pf, bb, Oa[nt], 0, 0, 0);
      }
    };
    pv_step(0);
    if (t != 16) pv_step(1);
  }

  float lt = l_acc;
  lt += __shfl_xor(lt, 16);
  lt += __shfl_xor(lt, 32);
  lt = fmaxf(lt, 1e-30f);
  #pragma unroll
  for (int nt = 0; nt < 4; ++nt)
    #pragma unroll
    for (int r = 0; r < 4; ++r) {
      const int qo = quad * 4 + r;
      const float lr = __shfl(lt, (lane & 48) | qo);
      const int qg2 = q0 + wave * 16 + qo;
      if (qg2 < SQ)
        out[((size_t)b * SQ + qg2) * DM + h * 64 + nt * 16 + l16] = f2bf(Oa[nt][r] / lr);
    }
}

// ---- yfin feature rows -> d_out fp32 (blocks 0..6143) + token outputs (blocks 6144..) ----
__global__ __launch_bounds__(256) void transpose_out(const u16* __restrict__ yf, float* __restrict__ out) {
  const int bx = blockIdx.x;
  const int tid = threadIdx.x;
  if (bx >= 6144) {                    // context + register token outputs
    const int idx = (bx - 6144) * 256 + tid;
    if (idx >= 8 * 5 * DM) return;
    const int b = idx / (5 * DM);
    const int r = idx % (5 * DM);
    const int s = r / DM, c = r % DM;
    const float v = bf2f(yf[((size_t)b * SQ + s) * DM + c]);
    if (s == 0) out[(size_t)6291456 + (size_t)b * DM + c] = v;
    else out[(size_t)6291456 + 6144 + ((size_t)b * 4 + (s - 1)) * DM + c] = v;
    return;
  }
  __shared__ u16 tile[32][33];
  const int b = bx / 768, rr = bx % 768, nt = rr / 24, ct = rr % 24;
  const int i = tid & 31, jj = tid >> 5;
  #pragma unroll
  for (int kk = 0; kk < 4; ++kk) {
    int j = jj + kk * 8;
    tile[j][i] = yf[((size_t)b * SQ + 5 + nt * 32 + j) * DM + ct * 32 + i];
  }
  __syncthreads();
  #pragma unroll
  for (int kk = 0; kk < 4; ++kk) {
    int j = jj + kk * 8;
    out[((size_t)b * 768 + ct * 32 + j) * 1024 + nt * 32 + i] = bf2f(tile[i][j]);
  }
}

extern "C" void kernel_launch(void* const* d_in, const int* in_sizes, int n_in,
                              void* d_out, int out_size, void* d_ws, size_t ws_size,
                              hipStream_t stream) {
  const float* x    = (const float*)d_in[0];
  const float* ctx  = (const float*)d_in[1];
  const float* regt = (const float*)d_in[2];
  const float* wqkv = (const float*)d_in[3];
  const float* bqkv = (const float*)d_in[4];
  const float* wout = (const float*)d_in[5];
  const float* bout = (const float*)d_in[6];
  const float* ln1s = (const float*)d_in[7];
  const float* ln1b = (const float*)d_in[8];
  const float* ln2s = (const float*)d_in[9];
  const float* ln2b = (const float*)d_in[10];
  const float* w1   = (const float*)d_in[11];
  const float* b1   = (const float*)d_in[12];
  const float* w2   = (const float*)d_in[13];
  const float* b2   = (const float*)d_in[14];

  char* ws = (char*)d_ws;
  u16* wb_all = (u16*)(ws + OFF_WQKV);
  u16* wqkv_b = (u16*)(ws + OFF_WQKV);
  u16* wout_b = (u16*)(ws + OFF_WOUT);
  u16* w1_b   = (u16*)(ws + OFF_W1);
  u16* w2_b   = (u16*)(ws + OFF_W2);
  u16* xwt    = (u16*)(ws + OFF_XWT);
  u16* qkv    = (u16*)(ws + OFF_QKV);   // 8320 x 2304 bf16
  u16* vtb    = (u16*)(ws + OFF_VT);
  u16* yb     = (u16*)(ws + OFF_Y);
  float* bqs  = (float*)(ws + OFF_BQ);
  u16* attnb  = (u16*)(ws + OFF_XF);    // scratch region
  u16* ynorm  = (u16*)(ws + OFF_XF);    // attnb dead after out_proj
  u16* h1     = (u16*)(ws + OFF_QKV);   // qkv/vt dead after attention
  u16* yfin   = (u16*)(ws + OFF_XWT);   // xwt dead after out_proj residual
  float* outp = (float*)d_out;

  convw_all   <<<6915, 256, 0, stream>>>(wqkv, wout, w1, w2, bqkv, wb_all, bqs);
  ln1_fused   <<<296, 256, 0, stream>>>(x, ctx, regt, ln1s, ln1b, xwt);
  gemmw<0, 768, 18><<<65 * 18, 128, 0, stream>>>(xwt, wqkv_b, bqs, nullptr, qkv, 8232);
  vtrans      <<<dim3(96, 34, 2), dim3(32, 8), 0, stream>>>(qkv, vtb);
  attn_flash  <<<dim3(96, 17), 256, 0, stream>>>(qkv, vtb, attnb);
  gemmk<1, 768, 6><<<65 * 6, 256, 0, stream>>>(attnb, wout_b, bout, xwt, yb, 8232);
  ln2k        <<<2058, 256, 0, stream>>>(yb, ln2s, ln2b, ynorm);
  gemmk<2, 768, 24><<<65 * 24, 256, 0, stream>>>(ynorm, w1_b, b1, nullptr, h1, 8232);
  gemmk<3, 3072, 6><<<65 * 6, 256, 0, stream>>>(h1, w2_b, b2, yb, yfin, 8232);
  transpose_out<<<6264, 256, 0, stream>>>(yfin, outp);
}

// Round 20
// 382.319 us; speedup vs baseline: 1.0133x; 1.0085x over previous
//
#include <hip/hip_runtime.h>
#include <hip/hip_bf16.h>
#include <cmath>

typedef unsigned short u16;
typedef __bf16 bf16x8 __attribute__((ext_vector_type(8)));
typedef float floatx4 __attribute__((ext_vector_type(4)));

#define SQ 1029
#define DM 768
#define NH 12
#define SQP 1088   // 17*64 tile coverage for attention
#define SSC 0.18033688011112042f   // 0.125 * log2(e), folded into q

// async global->LDS, 16B per lane; LDS dest = wave-uniform base + lane*16
#define GLD16(gp, lp) __builtin_amdgcn_global_load_lds( \
    (const __attribute__((address_space(1))) unsigned int*)(gp), \
    (__attribute__((address_space(3))) unsigned int*)(lp), 16, 0, 0)

// ---- workspace layout (bytes) ----
#define OFF_WQKV ((size_t)0)
#define OFF_WOUT ((size_t)3538944)
#define OFF_W1   ((size_t)4718592)
#define OFF_W2   ((size_t)9437184)
#define OFF_XF   ((size_t)14155776)
#define OFF_XWT  ((size_t)26800128)
#define OFF_QKV  ((size_t)39444480)
#define OFF_VT   ((size_t)77783040)
#define OFF_Y    ((size_t)91152384)
#define OFF_BQ   ((size_t)103796736)   // 2304 fp32 scaled qkv bias

__device__ __forceinline__ float bf2f(u16 u) {
  unsigned int x = ((unsigned int)u) << 16;
  float f; __builtin_memcpy(&f, &x, 4); return f;
}
__device__ __forceinline__ u16 f2bf(float f) {
  unsigned int x; __builtin_memcpy(&x, &f, 4);
  x = (x + 0x7fffu + ((x >> 16) & 1u)) >> 16;   // RNE
  return (u16)x;
}
__device__ __forceinline__ unsigned int pk_bf16(float a, float b) {
  __hip_bfloat162 h = __float22bfloat162_rn(make_float2(a, b));
  unsigned int u; __builtin_memcpy(&u, &h, 4); return u;
}

__device__ __forceinline__ void blockReduce2(float& s1, float& s2) {
  #pragma unroll
  for (int o = 32; o > 0; o >>= 1) { s1 += __shfl_xor(s1, o); s2 += __shfl_xor(s2, o); }
  __shared__ float t1[4], t2[4];
  const int w = threadIdx.x >> 6;
  if ((threadIdx.x & 63) == 0) { t1[w] = s1; t2[w] = s2; }
  __syncthreads();
  s1 = t1[0] + t1[1] + t1[2] + t1[3];
  s2 = t2[0] + t2[1] + t2[2] + t2[3];
}

// ---- all fp32 weights -> bf16 (q rows pre-scaled) + scaled qkv bias, one launch ----
__global__ __launch_bounds__(256) void convw_all(
    const float* __restrict__ a, const float* __restrict__ b,
    const float* __restrict__ c, const float* __restrict__ d,
    const float* __restrict__ bq, u16* __restrict__ dst, float* __restrict__ bqs) {
  int i = blockIdx.x * 256 + threadIdx.x;
  if (i >= 1770048) return;
  if (i >= 1769472) {                      // qkv bias tail: 576 float4 = 2304 fp32
    const int off = i - 1769472;
    float4 v = ((const float4*)bq)[off];
    if (off < 192) { v.x *= SSC; v.y *= SSC; v.z *= SSC; v.w *= SSC; }  // q entries
    ((float4*)bqs)[off] = v;
    return;
  }
  const float* src; int off;
  if (i < 442368)       { src = a; off = i; }
  else if (i < 589824)  { src = b; off = i - 442368; }
  else if (i < 1179648) { src = c; off = i - 589824; }
  else                  { src = d; off = i - 1179648; }
  float4 v = ((const float4*)src)[off];
  if (i < 147456) { v.x *= SSC; v.y *= SSC; v.z *= SSC; v.w *= SSC; }  // q rows of wqkv
  ushort4 o; o.x = f2bf(v.x); o.y = f2bf(v.y); o.z = f2bf(v.z); o.w = f2bf(v.w);
  ((ushort4*)dst)[i] = o;
}

// ---- LN1: feature rows (fused transpose, blocks 0..255) + token rows (blocks 256..295) ----
__global__ __launch_bounds__(256) void ln1_fused(
    const float* __restrict__ x, const float* __restrict__ ctx, const float* __restrict__ regt,
    const float* __restrict__ g, const float* __restrict__ be, u16* __restrict__ xwt) {
  const int bx = blockIdx.x;
  const int tid = threadIdx.x;
  if (bx >= 256) {                     // token rows: tokens+PE, LN1
    const int row = bx - 256;          // 0..39
    const int b = row / 5, s = row % 5;
    float v[3];
    #pragma unroll
    for (int i = 0; i < 3; ++i) {
      const int c = tid + i * 256;
      float tok = (s == 0) ? ctx[c] : regt[(s - 1) * DM + c];
      float e = (float)(2 * (c / 2)) * (1.0f / 768.0f);
      float ang = (float)s / powf(10000.0f, e);
      v[i] = tok + ((c & 1) ? cosf(ang) : sinf(ang));
    }
    float s1 = v[0] + v[1] + v[2];
    float s2 = v[0] * v[0] + v[1] * v[1] + v[2] * v[2];
    blockReduce2(s1, s2);
    const float mean = s1 * (1.0f / 768.0f);
    const float var = s2 * (1.0f / 768.0f) - mean * mean;
    const float rs = rsqrtf(fmaxf(var, 0.0f) + 1e-5f);
    #pragma unroll
    for (int i = 0; i < 3; ++i) {
      const int c = tid + i * 256;
      xwt[((size_t)b * SQ + s) * DM + c] = f2bf((v[i] - mean) * rs * g[c] + be[c]);
    }
    return;
  }
  // feature rows: x fp32 (8,768,1024) -> xwt rows 5.. ; 4 waves x 8 rows
  __shared__ u16 XT[32][772];
  const int b = bx >> 5, st = bx & 31;
  const int i2 = tid & 15, cj = tid >> 4;
  const int n0 = st * 32;
  #pragma unroll 4
  for (int ct = 0; ct < 48; ++ct) {
    const int c = ct * 16 + cj;
    const float2 v = *(const float2*)&x[((size_t)b * 768 + c) * 1024 + n0 + i2 * 2];
    XT[i2 * 2][c]     = f2bf(v.x);
    XT[i2 * 2 + 1][c] = f2bf(v.y);
  }
  __syncthreads();
  const int wave = tid >> 6, lane = tid & 63;
  float gr[12], br[12];
  #pragma unroll
  for (int k = 0; k < 12; ++k) { gr[k] = g[lane + k * 64]; br[k] = be[lane + k * 64]; }
  #pragma unroll
  for (int rr = 0; rr < 8; ++rr) {
    const int row = wave * 8 + rr;
    float v[12];
    float s1 = 0.f, s2 = 0.f;
    #pragma unroll
    for (int k = 0; k < 12; ++k) {
      v[k] = bf2f(XT[row][lane + k * 64]);
      s1 += v[k]; s2 += v[k] * v[k];
    }
    #pragma unroll
    for (int o = 32; o > 0; o >>= 1) { s1 += __shfl_xor(s1, o); s2 += __shfl_xor(s2, o); }
    const float mean = s1 * (1.0f / 768.0f);
    const float var = s2 * (1.0f / 768.0f) - mean * mean;
    const float rs = rsqrtf(fmaxf(var, 0.0f) + 1e-5f);
    u16* dst = xwt + ((size_t)b * SQ + 5 + n0 + row) * DM;
    #pragma unroll
    for (int k = 0; k < 12; ++k)
      dst[lane + k * 64] = f2bf((v[k] - mean) * rs * gr[k] + br[k]);
  }
}

// ---- LN2 vectorized: wave-per-row, ushort4 loads (8B/lane), uint2 stores ----
__global__ __launch_bounds__(256) void ln2k(
    const u16* __restrict__ y, const float* __restrict__ g, const float* __restrict__ be,
    u16* __restrict__ out) {
  const int row = blockIdx.x * 4 + (threadIdx.x >> 6);
  const int lane = threadIdx.x & 63;
  const u16* src = y + (size_t)row * DM;
  float v[12];
  float s1 = 0.f, s2 = 0.f;
  #pragma unroll
  for (int k = 0; k < 3; ++k) {
    const ushort4 u = *(const ushort4*)&src[k * 256 + lane * 4];
    const float a0 = bf2f(u.x), a1 = bf2f(u.y), a2 = bf2f(u.z), a3 = bf2f(u.w);
    v[k * 4 + 0] = a0; v[k * 4 + 1] = a1; v[k * 4 + 2] = a2; v[k * 4 + 3] = a3;
    s1 += (a0 + a1) + (a2 + a3);
    s2 += (a0 * a0 + a1 * a1) + (a2 * a2 + a3 * a3);
  }
  #pragma unroll
  for (int o = 32; o > 0; o >>= 1) { s1 += __shfl_xor(s1, o); s2 += __shfl_xor(s2, o); }
  const float mean = s1 * (1.0f / 768.0f);
  const float var = s2 * (1.0f / 768.0f) - mean * mean;
  const float rs = rsqrtf(fmaxf(var, 0.0f) + 1e-5f);
  u16* dst = out + (size_t)row * DM;
  #pragma unroll
  for (int k = 0; k < 3; ++k) {
    const float4 g4 = *(const float4*)&g[k * 256 + lane * 4];
    const float4 b4 = *(const float4*)&be[k * 256 + lane * 4];
    uint2 w;
    w.x = pk_bf16((v[k * 4 + 0] - mean) * rs * g4.x + b4.x,
                  (v[k * 4 + 1] - mean) * rs * g4.y + b4.y);
    w.y = pk_bf16((v[k * 4 + 2] - mean) * rs * g4.z + b4.z,
                  (v[k * 4 + 3] - mean) * rs * g4.w + b4.w);
    *(uint2*)&dst[k * 256 + lane * 4] = w;
  }
}

// ---- 128x128 GEMM, 4 waves (64x64/wave), BK=64 — proven baseline (out_proj, ffn1, ffn2) ----
template<int EPI, int K, int NB>
__global__ __launch_bounds__(256) void gemmk(
    const u16* __restrict__ A, const u16* __restrict__ W, const float* __restrict__ bias,
    const u16* __restrict__ res, u16* __restrict__ out, int M) {
  constexpr int N = NB * 128;
  __shared__ u16 SM[16384];
  u16* Asm = SM;
  u16* Bsm = SM + 8192;
  const int tid = threadIdx.x, wave = tid >> 6, lane = tid & 63, quad = lane >> 4, l16 = lane & 15;
  const int lin = blockIdx.x;
  constexpr int FULL = 64 * NB;
  int mb, nb;
  if (lin < FULL) { const int g = lin / (8 * NB); const int r = lin - g * 8 * NB; mb = g * 8 + (r & 7); nb = r >> 3; }
  else { mb = 64; nb = lin - FULL; }
  const int m0 = mb * 128, n0 = nb * 128;
  const int wm = wave & 1, wn = wave >> 1;

  const u16* Ap[4]; const u16* Wp[4]; u16* la[4]; u16* lb[4];
  #pragma unroll
  for (int it = 0; it < 4; ++it) {
    const int c = it * 256 + tid;
    const int row = c >> 3, gch = (c & 7) ^ (row & 7);
    Ap[it] = A + (size_t)min(m0 + row, M - 1) * K + gch * 8;
    Wp[it] = W + (size_t)(n0 + row) * K + gch * 8;
    la[it] = Asm + c * 8;
    lb[it] = Bsm + c * 8;
  }

  floatx4 acc[4][4];
  #pragma unroll
  for (int i = 0; i < 4; ++i)
    #pragma unroll
    for (int j = 0; j < 4; ++j) { floatx4 z = {0.f, 0.f, 0.f, 0.f}; acc[i][j] = z; }

  const int ch0 = (quad ^ (l16 & 7)) << 3;
  const int ch1 = ((4 + quad) ^ (l16 & 7)) << 3;

  #pragma unroll 1
  for (int ko = 0; ko < K / 768; ++ko) {
    #pragma unroll
    for (int ki = 0; ki < 768; ki += 64) {
      __syncthreads();
      #pragma unroll
      for (int it = 0; it < 4; ++it) GLD16(Ap[it] + ki, la[it]);
      #pragma unroll
      for (int it = 0; it < 4; ++it) GLD16(Wp[it] + ki, lb[it]);
      __syncthreads();
      #pragma unroll
      for (int kk = 0; kk < 2; ++kk) {
        const int ch = kk ? ch1 : ch0;
        bf16x8 a[4], b[4];
        #pragma unroll
        for (int i = 0; i < 4; ++i) a[i] = *(const bf16x8*)&Asm[(wm * 64 + i * 16 + l16) * 64 + ch];
        #pragma unroll
        for (int j = 0; j < 4; ++j) b[j] = *(const bf16x8*)&Bsm[(wn * 64 + j * 16 + l16) * 64 + ch];
        #pragma unroll
        for (int i = 0; i < 4; ++i)
          #pragma unroll
          for (int j = 0; j < 4; ++j)
            acc[i][j] = __builtin_amdgcn_mfma_f32_16x16x32_bf16(b[j], a[i], acc[i][j], 0, 0, 0);
      }
    }
    if (K > 768) {
      #pragma unroll
      for (int it = 0; it < 4; ++it) { Ap[it] += 768; Wp[it] += 768; }
    }
  }

  #pragma unroll
  for (int j = 0; j < 4; ++j) {
    const float4 b4 = *(const float4*)(bias + n0 + wn * 64 + j * 16 + quad * 4);
    #pragma unroll
    for (int i = 0; i < 4; ++i) {
      acc[i][j][0] += b4.x; acc[i][j][1] += b4.y; acc[i][j][2] += b4.z; acc[i][j][3] += b4.w;
    }
  }
  if constexpr (EPI == 2) {
    #pragma unroll
    for (int i = 0; i < 4; ++i)
      #pragma unroll
      for (int j = 0; j < 4; ++j)
        #pragma unroll
        for (int r = 0; r < 4; ++r) {
          const float v = acc[i][j][r];
          acc[i][j][r] = v / (1.0f + exp2f(-2.3022221f * (v + 0.044715f * v * v * v)));
        }
  }
  __syncthreads();
  u16* Ep = SM + wave * 2304;
  #pragma unroll
  for (int h = 0; h < 2; ++h) {
    #pragma unroll
    for (int i2 = 0; i2 < 2; ++i2) {
      const int i = h * 2 + i2;
      #pragma unroll
      for (int j = 0; j < 4; ++j) {
        uint2 w;
        w.x = pk_bf16(acc[i][j][0], acc[i][j][1]);
        w.y = pk_bf16(acc[i][j][2], acc[i][j][3]);
        *(uint2*)&Ep[(i2 * 16 + l16) * 72 + j * 16 + quad * 4] = w;
      }
    }
    #pragma unroll
    for (int s = 0; s < 4; ++s) {
      const int lrow = s * 8 + (lane >> 3);
      const int gm = m0 + wm * 64 + h * 32 + lrow;
      const int gn = n0 + wn * 64 + (lane & 7) * 8;
      uint4 lv = *(const uint4*)&Ep[lrow * 72 + (lane & 7) * 8];
      if constexpr (EPI == 1 || EPI == 3) {
        const uint4 rv = *(const uint4*)(res + (size_t)min(gm, M - 1) * N + gn);
        const unsigned* lp = &lv.x; const unsigned* rp = &rv.x;
        uint4 ov; unsigned* op = &ov.x;
        #pragma unroll
        for (int d = 0; d < 4; ++d) {
          const float a0 = bf2f((u16)(lp[d] & 0xffffu)) + bf2f((u16)(rp[d] & 0xffffu));
          const float a1 = bf2f((u16)(lp[d] >> 16)) + bf2f((u16)(rp[d] >> 16));
          op[d] = pk_bf16(a0, a1);
        }
        lv = ov;
      }
      if (gm < M) *(uint4*)(out + (size_t)gm * N + gn) = lv;
    }
  }
}

// ---- 128x128 GEMM, 2 waves (128x64/wave, acc[8][4]) — wide-grid GEMM (qkv) ----
template<int EPI, int K, int NB>
__global__ __launch_bounds__(128, 2) void gemmw(
    const u16* __restrict__ A, const u16* __restrict__ W, const float* __restrict__ bias,
    const u16* __restrict__ res, u16* __restrict__ out, int M) {
  constexpr int N = NB * 128;
  __shared__ u16 SM[16384];            // A[128][64] @0, B[128][64] @8192 (u16)
  u16* Asm = SM;
  u16* Bsm = SM + 8192;
  const int tid = threadIdx.x, wave = tid >> 6, lane = tid & 63, quad = lane >> 4, l16 = lane & 15;
  const int lin = blockIdx.x;
  constexpr int FULL = 64 * NB;
  int mb, nb;
  if (lin < FULL) { const int g = lin / (8 * NB); const int r = lin - g * 8 * NB; mb = g * 8 + (r & 7); nb = r >> 3; }
  else { mb = 64; nb = lin - FULL; }
  const int m0 = mb * 128, n0 = nb * 128;

  const u16* Ap[8]; const u16* Wp[8];
  #pragma unroll
  for (int it = 0; it < 8; ++it) {
    const int row = it * 16 + (tid >> 3);
    const int gch = (tid & 7) ^ (row & 7);
    Ap[it] = A + (size_t)min(m0 + row, M - 1) * K + gch * 8;
    Wp[it] = W + (size_t)(n0 + row) * K + gch * 8;
  }

  floatx4 acc[8][4];
  #pragma unroll
  for (int i = 0; i < 8; ++i)
    #pragma unroll
    for (int j = 0; j < 4; ++j) { floatx4 z = {0.f, 0.f, 0.f, 0.f}; acc[i][j] = z; }

  const int ch0 = (quad ^ (l16 & 7)) << 3;
  const int ch1 = ((4 + quad) ^ (l16 & 7)) << 3;

  #pragma unroll 1
  for (int ko = 0; ko < K / 768; ++ko) {
    #pragma unroll
    for (int ki = 0; ki < 768; ki += 64) {
      __syncthreads();
      #pragma unroll
      for (int it = 0; it < 8; ++it) GLD16(Ap[it] + ki, (char*)SM + (it * 128 + tid) * 16);
      #pragma unroll
      for (int it = 0; it < 8; ++it) GLD16(Wp[it] + ki, (char*)SM + 16384 + (it * 128 + tid) * 16);
      __syncthreads();
      #pragma unroll
      for (int kk = 0; kk < 2; ++kk) {
        const int ch = kk ? ch1 : ch0;
        bf16x8 a[8], b[4];
        #pragma unroll
        for (int i = 0; i < 8; ++i) a[i] = *(const bf16x8*)&Asm[(i * 16 + l16) * 64 + ch];
        #pragma unroll
        for (int j = 0; j < 4; ++j) b[j] = *(const bf16x8*)&Bsm[(wave * 64 + j * 16 + l16) * 64 + ch];
        #pragma unroll
        for (int i = 0; i < 8; ++i)
          #pragma unroll
          for (int j = 0; j < 4; ++j)
            acc[i][j] = __builtin_amdgcn_mfma_f32_16x16x32_bf16(b[j], a[i], acc[i][j], 0, 0, 0);
      }
    }
    if (K > 768) {
      #pragma unroll
      for (int it = 0; it < 8; ++it) { Ap[it] += 768; Wp[it] += 768; }
    }
  }

  #pragma unroll
  for (int j = 0; j < 4; ++j) {
    const float4 b4 = *(const float4*)(bias + n0 + wave * 64 + j * 16 + quad * 4);
    #pragma unroll
    for (int i = 0; i < 8; ++i) {
      acc[i][j][0] += b4.x; acc[i][j][1] += b4.y; acc[i][j][2] += b4.z; acc[i][j][3] += b4.w;
    }
  }
  if constexpr (EPI == 2) {
    #pragma unroll
    for (int i = 0; i < 8; ++i)
      #pragma unroll
      for (int j = 0; j < 4; ++j)
        #pragma unroll
        for (int r = 0; r < 4; ++r) {
          const float v = acc[i][j][r];
          acc[i][j][r] = v / (1.0f + exp2f(-2.3022221f * (v + 0.044715f * v * v * v)));
        }
  }
  __syncthreads();
  u16* Ep = SM + wave * 2304;
  #pragma unroll
  for (int g = 0; g < 4; ++g) {
    #pragma unroll
    for (int i2 = 0; i2 < 2; ++i2) {
      const int i = g * 2 + i2;
      #pragma unroll
      for (int j = 0; j < 4; ++j) {
        uint2 w;
        w.x = pk_bf16(acc[i][j][0], acc[i][j][1]);
        w.y = pk_bf16(acc[i][j][2], acc[i][j][3]);
        *(uint2*)&Ep[(i2 * 16 + l16) * 72 + j * 16 + quad * 4] = w;
      }
    }
    #pragma unroll
    for (int s = 0; s < 4; ++s) {
      const int lrow = s * 8 + (lane >> 3);
      const int gm = m0 + g * 32 + lrow;
      const int gn = n0 + wave * 64 + (lane & 7) * 8;
      uint4 lv = *(const uint4*)&Ep[lrow * 72 + (lane & 7) * 8];
      if constexpr (EPI == 1 || EPI == 3) {
        const uint4 rv = *(const uint4*)(res + (size_t)min(gm, M - 1) * N + gn);
        const unsigned* lp = &lv.x; const unsigned* rp = &rv.x;
        uint4 ov; unsigned* op = &ov.x;
        #pragma unroll
        for (int d = 0; d < 4; ++d) {
          const float a0 = bf2f((u16)(lp[d] & 0xffffu)) + bf2f((u16)(rp[d] & 0xffffu));
          const float a1 = bf2f((u16)(lp[d] >> 16)) + bf2f((u16)(rp[d] >> 16));
          op[d] = pk_bf16(a0, a1);
        }
        lv = ov;
      }
      if (gm < M) *(uint4*)(out + (size_t)gm * N + gn) = lv;
    }
  }
}

// ---- v-section of qkv (strided) -> vt (bh, dh:64, s:1088) ----
__global__ __launch_bounds__(256) void vtrans(const u16* __restrict__ qkv, u16* __restrict__ vt) {
  __shared__ u16 t[32][33];
  const int bh = blockIdx.x, st = blockIdx.y, dt = blockIdx.z;
  const int bq = bh / NH, hh = bh % NH;
  u16* vd = vt + (size_t)bh * 64 * SQP;
  const int i = threadIdx.x, jj = threadIdx.y;
  #pragma unroll
  for (int kk = 0; kk < 4; ++kk) {
    int j = jj + kk * 8;   // j: s-local, i: d-local
    t[j][i] = qkv[(size_t)(bq * SQ + st * 32 + j) * 2304 + 1536 + hh * 64 + dt * 32 + i];
  }
  __syncthreads();
  #pragma unroll
  for (int kk = 0; kk < 4; ++kk) {
    int j = jj + kk * 8;   // j: d-local, i: s-local
    vd[(size_t)(dt * 32 + j) * SQP + st * 32 + i] = t[i][j];
  }
}

// ---- flash attention v3: 64 queries/block, Q direct-to-register, 25.25KB LDS ----
__global__ __launch_bounds__(256) void attn_flash(
    const u16* __restrict__ qkv, const u16* __restrict__ vt, u16* __restrict__ out) {
  const int bh = blockIdx.x, qt = blockIdx.y;   // bh fast: head slabs stay L2-resident
  const int b = bh / NH, h = bh % NH;
  const int tid = threadIdx.x, wave = tid >> 6, lane = tid & 63, quad = lane >> 4, l16 = lane & 15;
  __shared__ u16 Ks[4096], VTs[4096];  // [64][64], chunk q^(row&7) swizzle
  __shared__ u16 Ps[64 * 72];          // P[query][key], +8 pad
  const int q0 = qt * 64;
  const u16* qk = qkv + (size_t)b * SQ * 2304 + h * 64;
  const u16* vslab = vt + (size_t)bh * 64 * SQP;
  const int r0 = tid >> 3,         q0c = (tid & 7) ^ (r0 & 7);
  const int r1 = (tid + 256) >> 3, q1c = (tid & 7) ^ (r1 & 7);
  u16* L0K = Ks + wave * 512;  u16* L1K = Ks + 2048 + wave * 512;
  u16* L0V = VTs + wave * 512; u16* L1V = VTs + 2048 + wave * 512;

  const int qrow = wave * 16 + l16;
  // Q A-fragments straight from global (swizzle cancels: needed global chunk = quad / 4+quad)
  const bf16x8 qf0 = *(const bf16x8*)&qk[(size_t)(q0 + qrow) * 2304 + quad * 8];
  const bf16x8 qf1 = *(const bf16x8*)&qk[(size_t)(q0 + qrow) * 2304 + (4 + quad) * 8];

  floatx4 Oa[4];
  #pragma unroll
  for (int nt = 0; nt < 4; ++nt) { floatx4 z = {0.f, 0.f, 0.f, 0.f}; Oa[nt] = z; }
  float l_acc = 0.f;
  const bool qfeat = (q0 + qrow >= 5);

  for (int t = 0; t < 17; ++t) {
    const int k0 = t * 64;
    __syncthreads();
    GLD16(qk + 768 + (size_t)(k0 + r0) * 2304 + q0c * 8, L0K);
    GLD16(qk + 768 + (size_t)(k0 + r1) * 2304 + q1c * 8, L1K);
    GLD16(vslab + (size_t)r0 * SQP + k0 + q0c * 8, L0V);
    GLD16(vslab + (size_t)r1 * SQP + k0 + q1c * 8, L1V);
    __syncthreads();  // drains vmcnt -> K/V tiles valid

    // S^T = K·Q^T : C[key = mt*16+quad*4+r][query = wave*16+l16]; pre-scaled
    floatx4 st[4];
    #pragma unroll
    for (int mt = 0; mt < 4; ++mt) { floatx4 z = {0.f, 0.f, 0.f, 0.f}; st[mt] = z; }
    #pragma unroll
    for (int kk = 0; kk < 2; ++kk) {
      const bf16x8 qf = kk ? qf1 : qf0;
      #pragma unroll
      for (int mt = 0; mt < 4; ++mt) {
        const int krow = mt * 16 + l16;
        bf16x8 kf = *(const bf16x8*)&Ks[krow * 64 + (((kk * 4 + quad) ^ (krow & 7)) << 3)];
        st[mt] = __builtin_amdgcn_mfma_f32_16x16x32_bf16(kf, qf, st[mt], 0, 0, 0);
      }
    }

    // softmax numerator; masks only on edge tiles
    if (t == 16) {
      // keys 1024..1087: valid only mt==0 && quad*4+r < 5
      float p[4];
      #pragma unroll
      for (int r = 0; r < 4; ++r) {
        float pv = exp2f(st[0][r]);
        p[r] = (quad * 4 + r < 5) ? pv : 0.f;
      }
      l_acc += (p[0] + p[1]) + (p[2] + p[3]);
      uint2 w;
      w.x = pk_bf16(p[0], p[1]);
      w.y = pk_bf16(p[2], p[3]);
      *(uint2*)&Ps[qrow * 72 + quad * 4] = w;
      const uint2 zz = {0u, 0u};
      #pragma unroll
      for (int mt = 1; mt < 4; ++mt) *(uint2*)&Ps[qrow * 72 + mt * 16 + quad * 4] = zz;
    } else if (t == 0) {
      #pragma unroll
      for (int mt = 0; mt < 4; ++mt) {
        float p[4];
        #pragma unroll
        for (int r = 0; r < 4; ++r) {
          float pv = exp2f(st[mt][r]);
          if (mt == 0) pv = (qfeat && (quad * 4 + r < 5)) ? 0.f : pv;
          p[r] = pv;
        }
        l_acc += (p[0] + p[1]) + (p[2] + p[3]);
        uint2 w;
        w.x = pk_bf16(p[0], p[1]);
        w.y = pk_bf16(p[2], p[3]);
        *(uint2*)&Ps[qrow * 72 + mt * 16 + quad * 4] = w;
      }
    } else {
      #pragma unroll
      for (int mt = 0; mt < 4; ++mt) {
        float p[4];
        #pragma unroll
        for (int r = 0; r < 4; ++r) p[r] = exp2f(st[mt][r]);
        l_acc += (p[0] + p[1]) + (p[2] + p[3]);
        uint2 w;
        w.x = pk_bf16(p[0], p[1]);
        w.y = pk_bf16(p[2], p[3]);
        *(uint2*)&Ps[qrow * 72 + mt * 16 + quad * 4] = w;
      }
    }

    // O += P·V  (per-wave P rows: no barrier). t==16: kk=1 half of P is all zero.
    auto pv_step = [&](int kk) {
      bf16x8 pf = *(const bf16x8*)&Ps[qrow * 72 + kk * 32 + quad * 8];
      #pragma unroll
      for (int nt = 0; nt < 4; ++nt) {
        const int brow = nt * 16 + l16;
        bf16x8 bb = *(const bf16x8*)&VTs[brow * 64 + (((kk * 4 + quad) ^ (brow & 7)) << 3)];
        Oa[nt] = __builtin_amdgcn_mfma_f32_16x16x32_bf16(pf, bb, Oa[nt], 0, 0, 0);
      }
    };
    pv_step(0);
    if (t != 16) pv_step(1);
  }

  float lt = l_acc;
  lt += __shfl_xor(lt, 16);
  lt += __shfl_xor(lt, 32);
  lt = fmaxf(lt, 1e-30f);
  #pragma unroll
  for (int nt = 0; nt < 4; ++nt)
    #pragma unroll
    for (int r = 0; r < 4; ++r) {
      const int qo = quad * 4 + r;
      const float lr = __shfl(lt, (lane & 48) | qo);
      const int qg2 = q0 + wave * 16 + qo;
      if (qg2 < SQ)
        out[((size_t)b * SQ + qg2) * DM + h * 64 + nt * 16 + l16] = f2bf(Oa[nt][r] / lr);
    }
}

// ---- yfin feature rows -> d_out fp32 (blocks 0..6143) + token outputs (blocks 6144..) ----
__global__ __launch_bounds__(256) void transpose_out(const u16* __restrict__ yf, float* __restrict__ out) {
  const int bx = blockIdx.x;
  const int tid = threadIdx.x;
  if (bx >= 6144) {                    // context + register token outputs
    const int idx = (bx - 6144) * 256 + tid;
    if (idx >= 8 * 5 * DM) return;
    const int b = idx / (5 * DM);
    const int r = idx % (5 * DM);
    const int s = r / DM, c = r % DM;
    const float v = bf2f(yf[((size_t)b * SQ + s) * DM + c]);
    if (s == 0) out[(size_t)6291456 + (size_t)b * DM + c] = v;
    else out[(size_t)6291456 + 6144 + ((size_t)b * 4 + (s - 1)) * DM + c] = v;
    return;
  }
  __shared__ u16 tile[32][33];
  const int b = bx / 768, rr = bx % 768, nt = rr / 24, ct = rr % 24;
  const int i = tid & 31, jj = tid >> 5;
  #pragma unroll
  for (int kk = 0; kk < 4; ++kk) {
    int j = jj + kk * 8;
    tile[j][i] = yf[((size_t)b * SQ + 5 + nt * 32 + j) * DM + ct * 32 + i];
  }
  __syncthreads();
  #pragma unroll
  for (int kk = 0; kk < 4; ++kk) {
    int j = jj + kk * 8;
    out[((size_t)b * 768 + ct * 32 + j) * 1024 + nt * 32 + i] = bf2f(tile[i][j]);
  }
}

extern "C" void kernel_launch(void* const* d_in, const int* in_sizes, int n_in,
                              void* d_out, int out_size, void* d_ws, size_t ws_size,
                              hipStream_t stream) {
  const float* x    = (const float*)d_in[0];
  const float* ctx  = (const float*)d_in[1];
  const float* regt = (const float*)d_in[2];
  const float* wqkv = (const float*)d_in[3];
  const float* bqkv = (const float*)d_in[4];
  const float* wout = (const float*)d_in[5];
  const float* bout = (const float*)d_in[6];
  const float* ln1s = (const float*)d_in[7];
  const float* ln1b = (const float*)d_in[8];
  const float* ln2s = (const float*)d_in[9];
  const float* ln2b = (const float*)d_in[10];
  const float* w1   = (const float*)d_in[11];
  const float* b1   = (const float*)d_in[12];
  const float* w2   = (const float*)d_in[13];
  const float* b2   = (const float*)d_in[14];

  char* ws = (char*)d_ws;
  u16* wb_all = (u16*)(ws + OFF_WQKV);
  u16* wqkv_b = (u16*)(ws + OFF_WQKV);
  u16* wout_b = (u16*)(ws + OFF_WOUT);
  u16* w1_b   = (u16*)(ws + OFF_W1);
  u16* w2_b   = (u16*)(ws + OFF_W2);
  u16* xwt    = (u16*)(ws + OFF_XWT);
  u16* qkv    = (u16*)(ws + OFF_QKV);   // 8320 x 2304 bf16
  u16* vtb    = (u16*)(ws + OFF_VT);
  u16* yb     = (u16*)(ws + OFF_Y);
  float* bqs  = (float*)(ws + OFF_BQ);
  u16* attnb  = (u16*)(ws + OFF_XF);    // scratch region
  u16* ynorm  = (u16*)(ws + OFF_XF);    // attnb dead after out_proj
  u16* h1     = (u16*)(ws + OFF_QKV);   // qkv/vt dead after attention
  u16* yfin   = (u16*)(ws + OFF_XWT);   // xwt dead after out_proj residual
  float* outp = (float*)d_out;

  convw_all   <<<6915, 256, 0, stream>>>(wqkv, wout, w1, w2, bqkv, wb_all, bqs);
  ln1_fused   <<<296, 256, 0, stream>>>(x, ctx, regt, ln1s, ln1b, xwt);
  gemmw<0, 768, 18><<<65 * 18, 128, 0, stream>>>(xwt, wqkv_b, bqs, nullptr, qkv, 8232);
  vtrans      <<<dim3(96, 34, 2), dim3(32, 8), 0, stream>>>(qkv, vtb);
  attn_flash  <<<dim3(96, 17), 256, 0, stream>>>(qkv, vtb, attnb);
  gemmk<1, 768, 6><<<65 * 6, 256, 0, stream>>>(attnb, wout_b, bout, xwt, yb, 8232);
  ln2k        <<<2058, 256, 0, stream>>>(yb, ln2s, ln2b, ynorm);
  gemmk<2, 768, 24><<<65 * 24, 256, 0, stream>>>(ynorm, w1_b, b1, nullptr, h1, 8232);
  gemmk<3, 3072, 6><<<65 * 6, 256, 0, stream>>>(h1, w2_b, b2, yb, yfin, 8232);
  transpose_out<<<6264, 256, 0, stream>>>(yfin, outp);
}